// Round 6
// baseline (280.512 us; speedup 1.0000x reference)
//
#include <hip/hip_runtime.h>
#include <cstdint>

#define DEVFN static __device__ __forceinline__

typedef __bf16 bf16x8 __attribute__((ext_vector_type(8)));
typedef float f32x4 __attribute__((ext_vector_type(4)));
typedef unsigned short us4 __attribute__((ext_vector_type(4)));

DEVFN unsigned short f2bf(float f) {
  unsigned u = __float_as_uint(f);
  u += 0x7fffu + ((u >> 16) & 1u);           // round-to-nearest-even
  return (unsigned short)(u >> 16);
}
DEVFN float bf2f(unsigned short h) { return __uint_as_float(((unsigned)h) << 16); }
DEVFN void async16(const void* g, void* l) {
  __builtin_amdgcn_global_load_lds((__attribute__((address_space(1))) const void*)g,
                                   (__attribute__((address_space(3))) void*)l, 16, 0, 0);
}
// gelu(tanh approx) == u * sigmoid(2z), z = 0.79788456*(u+0.044715u^3)  (exact identity)
DEVFN float gelu_t(float u) {
  float z = 0.7978845608028654f * (u + 0.044715f * u * u * u);
  float zc = fminf(fmaxf(z, -15.f), 15.f);
  float e = __expf(2.f * zc);
  return u * __fdividef(e, e + 1.f);
}
// XCD swizzle: lin%8 = XCD class; give each XCD a contiguous slice of g-space
DEVFN int xcd_swizzle(int lin, int total) {
  return (lin & 7) * (total >> 3) + (lin >> 3);
}

// ---------------- merged prep: rope + 5 transposes + LN1 --------------------
struct PrepArgs {
  float* rope;
  const float* W[5]; unsigned short* Wt[5]; float* cn[5];
  int N[5]; int off[6];
  const float* x; const float* g1s; unsigned short* h1; float* hrow1;
};
__global__ __launch_bounds__(256) void k_prep(PrepArgs a) {
  __shared__ float tile[32][33];
  __shared__ float part[8][32];
  __shared__ float red[12];
  const int bid = blockIdx.x, tid = threadIdx.x;
  if (bid < 256) {                       // rope table
    int g = bid * 256 + tid;
    int t = g >> 6, dd = g & 63, i = dd & 31;
    float fr = __expf(-0.2878231366242558f * (float)i);   // ln(1e4)/32
    float ang = (float)t * fr;
    a.rope[g] = (dd < 32) ? cosf(ang) : sinf(ang);
  } else if (bid < 9472) {               // weight transpose + col sq-norms
    int lin = bid - 256;
    int e = 0;
    while (lin >= a.off[e + 1]) ++e;
    int local = lin - a.off[e];
    const int N = a.N[e];
    int nbx = N >> 5;
    int tn = local % nbx, tk = local / nbx;
    const float* W = a.W[e];
    unsigned short* Wt = a.Wt[e];
    float* cn = a.cn[e];
    const int K = (e == 4) ? 3072 : 768;
    int tx = tid & 31, ty = tid >> 5;
    float acc = 0.f;
    #pragma unroll
    for (int j = 0; j < 4; ++j) {
      int r = ty + j * 8;
      float v = W[(long)(tk * 32 + r) * N + tn * 32 + tx];
      tile[r][tx] = v;
      acc += v * v;
    }
    part[ty][tx] = acc;
    __syncthreads();
    #pragma unroll
    for (int j = 0; j < 4; ++j) {
      int rr = ty + j * 8;
      Wt[(long)(tn * 32 + rr) * K + tk * 32 + tx] = f2bf(tile[tx][rr]);
    }
    if (ty == 0) {
      float s = part[0][tx];
      #pragma unroll
      for (int jj = 1; jj < 8; ++jj) s += part[jj][tx];
      atomicAdd(&cn[tn * 32 + tx], s);
    }
  } else {                               // LN1
    int row = bid - 9472;
    const float* xr = a.x + (long)row * 768;
    float v0 = xr[tid], v1 = xr[tid + 256], v2 = xr[tid + 512];
    float s = v0 + v1 + v2;
    float ss = v0 * v0 + v1 * v1 + v2 * v2;
    #pragma unroll
    for (int o = 32; o; o >>= 1) { s += __shfl_xor(s, o); ss += __shfl_xor(ss, o); }
    int wv = tid >> 6;
    if ((tid & 63) == 0) { red[wv] = s; red[wv + 4] = ss; }
    __syncthreads();
    s = red[0] + red[1] + red[2] + red[3];
    ss = red[4] + red[5] + red[6] + red[7];
    float mu = s * (1.f / 768.f);
    float var = ss * (1.f / 768.f) - mu * mu;
    float rs = rsqrtf(var + 1e-6f);
    float h0 = (v0 - mu) * rs * a.g1s[tid];
    float h1 = (v1 - mu) * rs * a.g1s[tid + 256];
    float h2 = (v2 - mu) * rs * a.g1s[tid + 512];
    unsigned short* hr = a.h1 + (long)row * 768;
    hr[tid] = f2bf(h0); hr[tid + 256] = f2bf(h1); hr[tid + 512] = f2bf(h2);
    float p = h0 * h0 + h1 * h1 + h2 * h2;
    #pragma unroll
    for (int o = 32; o; o >>= 1) p += __shfl_xor(p, o);
    if ((tid & 63) == 0) red[8 + wv] = p;
    __syncthreads();
    if (tid == 0) a.hrow1[row] = red[8] + red[9] + red[10] + red[11];
  }
}

// ---------------- layernorm (f32 in) -> bf16 h + row sum(h^2) ---------------
__global__ __launch_bounds__(256) void k_ln(const float* __restrict__ x,
    const float* __restrict__ g, unsigned short* __restrict__ h, float* __restrict__ row2) {
  int row = blockIdx.x, tid = threadIdx.x;
  const float* xr = x + (long)row * 768;
  float v0 = xr[tid], v1 = xr[tid + 256], v2 = xr[tid + 512];
  float s = v0 + v1 + v2;
  float ss = v0 * v0 + v1 * v1 + v2 * v2;
  #pragma unroll
  for (int o = 32; o; o >>= 1) { s += __shfl_xor(s, o); ss += __shfl_xor(ss, o); }
  __shared__ float red[12];
  int wv = tid >> 6;
  if ((tid & 63) == 0) { red[wv] = s; red[wv + 4] = ss; }
  __syncthreads();
  s = red[0] + red[1] + red[2] + red[3];
  ss = red[4] + red[5] + red[6] + red[7];
  float mu = s * (1.f / 768.f);
  float var = ss * (1.f / 768.f) - mu * mu;
  float rs = rsqrtf(var + 1e-6f);
  float h0 = (v0 - mu) * rs * g[tid];
  float h1 = (v1 - mu) * rs * g[tid + 256];
  float h2 = (v2 - mu) * rs * g[tid + 512];
  unsigned short* hr = h + (long)row * 768;
  hr[tid] = f2bf(h0); hr[tid + 256] = f2bf(h1); hr[tid + 512] = f2bf(h2);
  float p = h0 * h0 + h1 * h1 + h2 * h2;
  #pragma unroll
  for (int o = 32; o; o >>= 1) p += __shfl_xor(p, o);
  if ((tid & 63) == 0) red[8 + wv] = p;
  __syncthreads();
  if (tid == 0) row2[row] = red[8] + red[9] + red[10] + red[11];
}

// ---------------- yat GEMM: 64x128 tile, 3-buffer distance-2, XCD swizzle ---
constexpr int M_QKV = 0, M_AO = 1, M_PART = 2;

struct GemmArgs {
  const unsigned short* A; const unsigned short* Bt;
  const float* arow2; const float* wcol2; const float* bias; const float* alpha;
  int N; int ks;
  const float* rope;                                    // QKV
  unsigned short* qo; unsigned short* ko; unsigned short* vo;  // QKV
  const float* xf; float* xo;                           // AO: residual in/out (f32)
  unsigned short* partb;                                // PART: bf16 slab base
};

template <int MODE, int NI, int NBM, int NBN, int NZ>
__global__ __launch_bounds__(256, 4) void k_gemm(GemmArgs p) {
  __shared__ __align__(16) unsigned short As[3][2048];   // 64 x 32
  __shared__ __align__(16) unsigned short Bs[3][4096];   // 128 x 32
  const int tid = threadIdx.x, wave = tid >> 6, lane = tid & 63;
  const int quad = lane >> 4, l = lane & 15;
  constexpr int TOTAL = NBM * NBN * NZ;
  const int g = xcd_swizzle(blockIdx.x, TOTAL);
  const int bm = (g % NBM) * 64;
  const int rest = g / NBM;
  const int bn = (rest % NBN) * 128;
  const int z = rest / NBN;
  const int kb = z * (NI * 32);
  const int ks = p.ks;
  const int wm = (wave & 1) * 32, wn = (wave >> 1) * 64;
  const f32x4 fzero = {0.f, 0.f, 0.f, 0.f};
  f32x4 acc[2][4];
  #pragma unroll
  for (int i = 0; i < 2; ++i)
    #pragma unroll
    for (int j = 0; j < 4; ++j) acc[i][j] = fzero;
  const int sw = (l >> 1) & 3;

  // hoisted per-thread staging pointers (advance +32 elements per stage call)
  const int r0 = tid >> 2;
  const int c0 = (tid & 3) ^ ((r0 >> 1) & 3);
  const unsigned short* ap  = p.A  + (long)(bm + r0) * ks + kb + c0 * 8;
  const unsigned short* bp0 = p.Bt + (long)(bn + r0) * ks + kb + c0 * 8;
  const unsigned short* bp1 = bp0 + (long)64 * ks;

  auto stage = [&](int s) {
    async16(ap,  &As[s][tid * 8]);
    async16(bp0, &Bs[s][tid * 8]);
    async16(bp1, &Bs[s][(tid + 256) * 8]);
    ap += 32; bp0 += 32; bp1 += 32;
  };
  auto compute = [&](int s) {
    bf16x8 af[2], bfv[4];
    #pragma unroll
    for (int mi = 0; mi < 2; ++mi)
      af[mi] = *(const bf16x8*)&As[s][(wm + mi * 16 + l) * 32 + ((quad ^ sw) * 8)];
    #pragma unroll
    for (int ni = 0; ni < 4; ++ni)
      bfv[ni] = *(const bf16x8*)&Bs[s][(wn + ni * 16 + l) * 32 + ((quad ^ sw) * 8)];
    #pragma unroll
    for (int mi = 0; mi < 2; ++mi)
      #pragma unroll
      for (int ni = 0; ni < 4; ++ni)
        acc[mi][ni] = __builtin_amdgcn_mfma_f32_16x16x32_bf16(af[mi], bfv[ni], acc[mi][ni], 0, 0, 0);
  };
  auto iter = [&](int s, int i) {
    if (i + 1 >= NI) { asm volatile("s_waitcnt vmcnt(0)" ::: "memory"); }
    else             { asm volatile("s_waitcnt vmcnt(3)" ::: "memory"); }
    __builtin_amdgcn_s_barrier();
    asm volatile("" ::: "memory");
    if (i + 2 < NI) stage(s == 0 ? 2 : s - 1);
    compute(s);
  };

  stage(0);
  stage(1);
  int i = 0;
  while (i < NI) {          // NI % 3 == 0
    iter(0, i); ++i;
    iter(1, i); ++i;
    iter(2, i); ++i;
  }

  if constexpr (MODE == M_PART) {
    unsigned short* slab = p.partb + (long)z * (2048 * 768);
    #pragma unroll
    for (int ni = 0; ni < 4; ++ni) {
      const int j = bn + wn + ni * 16 + l;
      #pragma unroll
      for (int mi = 0; mi < 2; ++mi) {
        const int i0 = bm + wm + mi * 16 + quad * 4;
        #pragma unroll
        for (int rg = 0; rg < 4; ++rg)
          slab[(long)(i0 + rg) * 768 + j] = f2bf(acc[mi][ni][rg]);
      }
    }
  } else {
    const float al = p.alpha[0];
    const float nn = (float)p.N;
    const float ys = powf(sqrtf(nn) / log1pf(nn), al);
    #pragma unroll
    for (int ni = 0; ni < 4; ++ni) {
      const int j = bn + wn + ni * 16 + l;
      const float w2 = p.wcol2[j];
      const float bj = p.bias[j];
      int s3 = 0, hh = 0, dd = 0;
      if constexpr (MODE == M_QKV) { s3 = j / 768; int rem = j - s3 * 768; hh = rem >> 6; dd = rem & 63; }
      #pragma unroll
      for (int mi = 0; mi < 2; ++mi) {
        const int i0 = bm + wm + mi * 16 + quad * 4;
        float vv[4];
        #pragma unroll
        for (int rg = 0; rg < 4; ++rg) {
          const float y = acc[mi][ni][rg];
          const float dist = p.arow2[i0 + rg] + w2 - 2.f * y + 1e-6f;
          vv[rg] = (__fdividef(y * y, dist) + bj) * ys;
        }
        if constexpr (MODE == M_QKV) {
          int b = i0 >> 10, t0 = i0 & 1023;
          if (s3 == 2) {
            us4 pk = {f2bf(vv[0]), f2bf(vv[1]), f2bf(vv[2]), f2bf(vv[3])};
            *(us4*)&p.vo[((long)(b * 12 + hh) * 64 + dd) * 1024 + t0] = pk;    // V^T (B,H,D,T)
          } else {
            unsigned short* dst = (s3 == 0) ? p.qo : p.ko;                     // (B,H,T,D)
            #pragma unroll
            for (int rg = 0; rg < 4; ++rg) {
              float ro = p.rope[(t0 + rg) * 64 + dd];
              dst[((long)(b * 12 + hh) * 1024 + t0 + rg) * 64 + dd] = f2bf(vv[rg] * ro);
            }
          }
        } else {  // M_AO
          #pragma unroll
          for (int rg = 0; rg < 4; ++rg) {
            long idx = (long)(i0 + rg) * 768 + j;
            p.xo[idx] = p.xf[idx] + vv[rg];
          }
        }
      }
    }
  }
}

// ---------------- PROJ reduce (4 bf16 slabs) + yat epilogue + residual ------
struct EpiArgs {
  const unsigned short* slab; const float* arow2; const float* wcol2;
  const float* bias; const float* alpha; const float* xo; float* outf;
};
__global__ __launch_bounds__(256) void k_proj_epi(EpiArgs p) {
  int g = blockIdx.x * 256 + threadIdx.x;   // 393216 = 2048*768/4
  int i = g / 192, jv = (g - i * 192) * 4;
  long base = (long)i * 768 + jv;
  f32x4 y = {0.f, 0.f, 0.f, 0.f};
  #pragma unroll
  for (int z = 0; z < 4; ++z) {
    us4 s4 = *(const us4*)(p.slab + (long)z * 1572864 + base);
    #pragma unroll
    for (int c = 0; c < 4; ++c) y[c] += bf2f(s4[c]);
  }
  const float a2 = p.arow2[i];
  const float ys = powf(sqrtf(768.f) / log1pf(768.f), p.alpha[0]);
  f32x4 xo4 = *(const f32x4*)(p.xo + base);
  f32x4 out;
  #pragma unroll
  for (int c = 0; c < 4; ++c) {
    float yy = y[c];
    float dist = a2 + p.wcol2[jv + c] - 2.f * yy + 1e-6f;
    out[c] = xo4[c] + (__fdividef(yy * yy, dist) + p.bias[jv + c]) * ys;
  }
  *(f32x4*)(p.outf + base) = out;
}

// ---- merged FC+GATE yat GEMM: 128x64 tile, A+B all LDS-staged, 3-buffer ----
// R6: reverted to the R4 best-measured version (43.6 us). R5's 8-wave variant
// doubled occupancy with zero speedup -> k_mlp is structure-limited; done.
struct MlpArgs {
  const unsigned short* A; const unsigned short* Bf; const unsigned short* Bg;
  const float* arow2; const float* w2f; const float* w2g;
  const float* bf; const float* bg; const float* af_; const float* ag_;
  unsigned short* mlp; float* mrow2;
};

__global__ __launch_bounds__(256, 3) void k_mlp(MlpArgs p) {
  constexpr int NI = 24, K = 768;
  __shared__ __align__(16) unsigned short As[3][4096];    // 128 x 32
  __shared__ __align__(16) unsigned short Bfs[3][2048];   // 64 x 32
  __shared__ __align__(16) unsigned short Bgs[3][2048];   // 64 x 32
  const int tid = threadIdx.x, wave = tid >> 6, lane = tid & 63;
  const int quad = lane >> 4, l = lane & 15;
  const int g = xcd_swizzle(blockIdx.x, 16 * 48);
  const int bm = (g % 16) * 128, bn = (g / 16) * 64;
  const int wm = wave * 32;                // 4 waves x 32 rows; all share 64 cols
  const f32x4 fzero = {0.f, 0.f, 0.f, 0.f};
  f32x4 accf[2][4], accg[2][4];
  #pragma unroll
  for (int i = 0; i < 2; ++i)
    #pragma unroll
    for (int j = 0; j < 4; ++j) { accf[i][j] = fzero; accg[i][j] = fzero; }
  const int sw = (l >> 1) & 3;

  // hoisted per-thread staging pointers (advance +32 elements per stage call)
  const int r0 = tid >> 2;
  const int c0 = (tid & 3) ^ ((r0 >> 1) & 3);
  const unsigned short* ap0 = p.A  + (long)(bm + r0) * K + c0 * 8;
  const unsigned short* ap1 = ap0 + (long)64 * K;
  const unsigned short* bfp = p.Bf + (long)(bn + r0) * K + c0 * 8;
  const unsigned short* bgp = p.Bg + (long)(bn + r0) * K + c0 * 8;

  auto stage = [&](int s) {
    async16(ap0, &As[s][tid * 8]);
    async16(ap1, &As[s][(tid + 256) * 8]);
    async16(bfp, &Bfs[s][tid * 8]);
    async16(bgp, &Bgs[s][tid * 8]);
    ap0 += 32; ap1 += 32; bfp += 32; bgp += 32;
  };
  auto compute = [&](int s) {
    bf16x8 af[2], bff[4], bfg[4];
    #pragma unroll
    for (int mi = 0; mi < 2; ++mi)
      af[mi] = *(const bf16x8*)&As[s][(wm + mi * 16 + l) * 32 + ((quad ^ sw) * 8)];
    #pragma unroll
    for (int ni = 0; ni < 4; ++ni) {
      bff[ni] = *(const bf16x8*)&Bfs[s][(ni * 16 + l) * 32 + ((quad ^ sw) * 8)];
      bfg[ni] = *(const bf16x8*)&Bgs[s][(ni * 16 + l) * 32 + ((quad ^ sw) * 8)];
    }
    __builtin_amdgcn_s_setprio(1);
    #pragma unroll
    for (int ni = 0; ni < 4; ++ni) {
      accf[0][ni] = __builtin_amdgcn_mfma_f32_16x16x32_bf16(af[0], bff[ni], accf[0][ni], 0, 0, 0);
      accg[0][ni] = __builtin_amdgcn_mfma_f32_16x16x32_bf16(af[0], bfg[ni], accg[0][ni], 0, 0, 0);
      accf[1][ni] = __builtin_amdgcn_mfma_f32_16x16x32_bf16(af[1], bff[ni], accf[1][ni], 0, 0, 0);
      accg[1][ni] = __builtin_amdgcn_mfma_f32_16x16x32_bf16(af[1], bfg[ni], accg[1][ni], 0, 0, 0);
    }
    __builtin_amdgcn_s_setprio(0);
  };
  auto iter = [&](int s, int i) {
    if (i + 1 >= NI) { asm volatile("s_waitcnt vmcnt(0)" ::: "memory"); }
    else             { asm volatile("s_waitcnt vmcnt(4)" ::: "memory"); }
    __builtin_amdgcn_s_barrier();
    asm volatile("" ::: "memory");
    if (i + 2 < NI) stage((i + 2) % 3);
    compute(s);
  };

  stage(0);
  stage(1);
  int i = 0;
  while (i < NI) {          // NI % 3 == 0
    iter(0, i); ++i;
    iter(1, i); ++i;
    iter(2, i); ++i;
  }

  const float ysf = powf(sqrtf(3072.f) / log1pf(3072.f), p.af_[0]);
  const float ysg = powf(sqrtf(3072.f) / log1pf(3072.f), p.ag_[0]);
  float w2f[4], w2g[4], bjf[4], bjg[4]; int js[4];
  #pragma unroll
  for (int ni = 0; ni < 4; ++ni) {
    int j = bn + ni * 16 + l;
    js[ni] = j; w2f[ni] = p.w2f[j]; w2g[ni] = p.w2g[j]; bjf[ni] = p.bf[j]; bjg[ni] = p.bg[j];
  }
  #pragma unroll
  for (int mi = 0; mi < 2; ++mi) {
    #pragma unroll
    for (int rg = 0; rg < 4; ++rg) {
      const int ii = bm + wm + mi * 16 + quad * 4 + rg;
      const float a2 = p.arow2[ii];
      float rsum = 0.f;
      #pragma unroll
      for (int ni = 0; ni < 4; ++ni) {
        float yf = accf[mi][ni][rg];
        float gate = (__fdividef(yf * yf, a2 + w2f[ni] - 2.f * yf + 1e-6f) + bjf[ni]) * ysf;
        float yg = accg[mi][ni][rg];
        float u  = (__fdividef(yg * yg, a2 + w2g[ni] - 2.f * yg + 1e-6f) + bjg[ni]) * ysg;
        float out = gelu_t(u) * gate;
        p.mlp[(long)ii * 3072 + js[ni]] = f2bf(out);
        rsum += out * out;
      }
      #pragma unroll
      for (int o = 8; o; o >>= 1) rsum += __shfl_xor(rsum, o);
      if (l == 0) atomicAdd(&p.mrow2[ii], rsum);
    }
  }
}

// ---------------- flash attention: 1-wave blocks, no staging, no barriers ---
// R6: K/V are L2-resident (6.3 MB) -> LDS staging + 4-wave lockstep was pure
// overhead (m169 pattern). Each wave owns 16 Q-rows; per KV tile: issue all
// K+V fragment loads, QK^T (waits K), softmax covers V's L2 latency, PV.
// 1536 independent blocks x 64 threads; only LDS use is the 2KB P-transpose.
__global__ __launch_bounds__(64) void k_attn(const unsigned short* __restrict__ qb,
    const unsigned short* __restrict__ kb, const unsigned short* __restrict__ vb,
    unsigned short* __restrict__ ob, float* __restrict__ orow2) {
  __shared__ __align__(16) unsigned short Ps[1024];   // 16 x 64, xor-swizzled
  const int lane = threadIdx.x & 63;
  const int quad = lane >> 4, l = lane & 15;
  const int g = xcd_swizzle(blockIdx.x, 64 * 24);
  const int bh = g % 24, qt = 63 - (g / 24);   // heavy q-tiles first
  const int b = bh / 12, hh = bh % 12;
  const int q0 = qt * 16;
  const int jlast = (q0 + 15) >> 6;
  const f32x4 fzero = {0.f, 0.f, 0.f, 0.f};

  // Q fragment direct from global: row q0+l, k-chunk (ks*4+quad)*8
  const unsigned short* qg = qb + ((long)bh * 1024 + q0) * 64;
  bf16x8 aq[2];
  #pragma unroll
  for (int ks = 0; ks < 2; ++ks)
    aq[ks] = *(const bf16x8*)(qg + l * 64 + (ks * 4 + quad) * 8);

  // per-lane fragment base pointers (K: (B,H,T,D); V^T: (B,H,D,T))
  const unsigned short* kpj = kb + ((long)bh * 1024 + l) * 64 + quad * 8;
  const unsigned short* vpj = vb + (long)bh * 65536 + (long)l * 1024 + quad * 8;

  f32x4 O[4];
  float mi_[4], li[4];
  #pragma unroll
  for (int f = 0; f < 4; ++f) O[f] = fzero;
  #pragma unroll
  for (int r = 0; r < 4; ++r) { mi_[r] = -1e30f; li[r] = 0.f; }

  for (int jt = 0; jt <= jlast; ++jt) {
    // issue all K and V fragment loads up front; V's latency hides under softmax
    bf16x8 bk[2][4], bv[2][4];
    #pragma unroll
    for (int f = 0; f < 4; ++f)
      #pragma unroll
      for (int ks = 0; ks < 2; ++ks) {
        bk[ks][f] = *(const bf16x8*)(kpj + f * 1024 + ks * 32);    // row f*16+l of K tile
        bv[ks][f] = *(const bf16x8*)(vpj + f * 16384 + ks * 32);   // d-row f*16+l of V^T
      }
    kpj += 4096;   // next 64 K-rows
    vpj += 64;     // next 64 t-columns

    f32x4 S[4];
    #pragma unroll
    for (int f = 0; f < 4; ++f) S[f] = fzero;
    #pragma unroll
    for (int ks = 0; ks < 2; ++ks)
      #pragma unroll
      for (int f = 0; f < 4; ++f)
        S[f] = __builtin_amdgcn_mfma_f32_16x16x32_bf16(aq[ks], bk[ks][f], S[f], 0, 0, 0);

    const bool diag = (jt == jlast);
    #pragma unroll
    for (int f = 0; f < 4; ++f)
      #pragma unroll
      for (int r = 0; r < 4; ++r) {
        float v = S[f][r] * 0.125f;
        if (diag && (jt * 64 + f * 16 + l > q0 + quad * 4 + r)) v = -1e30f;
        S[f][r] = v;
      }
    #pragma unroll
    for (int r = 0; r < 4; ++r) {
      float mx = fmaxf(fmaxf(S[0][r], S[1][r]), fmaxf(S[2][r], S[3][r]));
      #pragma unroll
      for (int o = 8; o; o >>= 1) mx = fmaxf(mx, __shfl_xor(mx, o));
      float mnew = fmaxf(mi_[r], mx);
      float alr = __expf(mi_[r] - mnew);
      float sum = 0.f;
      #pragma unroll
      for (int f = 0; f < 4; ++f) {
        float e = __expf(S[f][r] - mnew);
        S[f][r] = e;
        sum += e;
      }
      #pragma unroll
      for (int o = 8; o; o >>= 1) sum += __shfl_xor(sum, o);
      li[r] = li[r] * alr + sum;
      #pragma unroll
      for (int f = 0; f < 4; ++f) O[f][r] *= alr;
      mi_[r] = mnew;
    }
    // P transpose through LDS (wave-internal; lgkmcnt only, no barrier)
    #pragma unroll
    for (int f = 0; f < 4; ++f)
      #pragma unroll
      for (int r = 0; r < 4; ++r) {
        int i = quad * 4 + r;
        int j = f * 16 + l;
        int pch = (j >> 3) ^ (i & 7);
        Ps[i * 64 + pch * 8 + (j & 7)] = f2bf(S[f][r]);
      }
    #pragma unroll
    for (int ks = 0; ks < 2; ++ks) {
      bf16x8 ap = *(const bf16x8*)&Ps[l * 64 + (((ks * 4 + quad) ^ (l & 7)) * 8)];
      #pragma unroll
      for (int f = 0; f < 4; ++f)
        O[f] = __builtin_amdgcn_mfma_f32_16x16x32_bf16(ap, bv[ks][f], O[f], 0, 0, 0);
    }
  }
  float inv[4];
  #pragma unroll
  for (int r = 0; r < 4; ++r) inv[r] = __fdividef(1.f, li[r]);
  #pragma unroll
  for (int f = 0; f < 4; ++f)
    #pragma unroll
    for (int r = 0; r < 4; ++r) {
      int t = q0 + quad * 4 + r;
      int dd = f * 16 + l;
      ob[((long)(b * 1024 + t) * 12 + hh) * 64 + dd] = f2bf(O[f][r] * inv[r]);  // (B,T,H,D)
    }
  #pragma unroll
  for (int r = 0; r < 4; ++r) {
    float rsum = 0.f;
    #pragma unroll
    for (int f = 0; f < 4; ++f) { float v = O[f][r] * inv[r]; rsum += v * v; }
    #pragma unroll
    for (int o = 8; o; o >>= 1) rsum += __shfl_xor(rsum, o);
    if (l == 0) {
      int t = q0 + quad * 4 + r;
      atomicAdd(&orow2[b * 1024 + t], rsum);
    }
  }
}

// ---------------- host ------------------------------------------------------
extern "C" void kernel_launch(void* const* d_in, const int* in_sizes, int n_in,
                              void* d_out, int out_size, void* d_ws, size_t ws_size,
                              hipStream_t stream) {
  (void)in_sizes; (void)n_in; (void)out_size;
  char* w = (char*)d_ws;
  size_t off = 0;
  auto alloc = [&](size_t bytes) -> void* {
    void* p = w + off;
    off = (off + bytes + 255) & ~(size_t)255;
    return p;
  };
  float* rope            = (float*)alloc(65536 * 4);
  unsigned short* wtqkv  = (unsigned short*)alloc((size_t)2304 * 768 * 2);
  unsigned short* wtao   = (unsigned short*)alloc((size_t)768 * 768 * 2);
  unsigned short* wtfc   = (unsigned short*)alloc((size_t)3072 * 768 * 2);
  unsigned short* wtgate = (unsigned short*)alloc((size_t)3072 * 768 * 2);
  unsigned short* wtproj = (unsigned short*)alloc((size_t)768 * 3072 * 2);
  float* zeroed          = (float*)alloc(14080 * 4);   // wcol2(9984) + orow2(2048) + mrow2(2048)
  unsigned short* h1     = (unsigned short*)alloc((size_t)2048 * 768 * 2);
  float* hrow1           = (float*)alloc(2048 * 4);
  unsigned short* qbuf   = (unsigned short*)alloc((size_t)2048 * 768 * 2);
  unsigned short* kbuf   = (unsigned short*)alloc((size_t)2048 * 768 * 2);
  unsigned short* vbuf   = (unsigned short*)alloc((size_t)2048 * 768 * 2);
  unsigned short* obuf   = (unsigned short*)alloc((size_t)2048 * 768 * 2);
  float* xo              = (float*)alloc((size_t)2048 * 768 * 4);
  unsigned short* h2     = (unsigned short*)alloc((size_t)2048 * 768 * 2);
  float* hrow2           = (float*)alloc(2048 * 4);
  unsigned short* mlp    = (unsigned short*)alloc((size_t)2048 * 3072 * 2);
  unsigned short* slabs  = (unsigned short*)alloc((size_t)4 * 2048 * 768 * 2);  // bf16 split-K partials
  if (off > ws_size) return;

  float* wcol2  = zeroed;
  float* orow2  = zeroed + 9984;
  float* mrow2  = zeroed + 9984 + 2048;
  float* c_qkv  = wcol2 + 0;
  float* c_ao   = wcol2 + 2304;
  float* c_fc   = wcol2 + 3072;
  float* c_gate = wcol2 + 6144;
  float* c_proj = wcol2 + 9216;

  const float* xin = (const float*)d_in[0];

  hipMemsetAsync(zeroed, 0, 14080 * 4, stream);

  PrepArgs pa;
  pa.rope = rope;
  pa.W[0] = (const float*)d_in[3];  pa.Wt[0] = wtqkv;  pa.cn[0] = c_qkv;  pa.N[0] = 2304;
  pa.W[1] = (const float*)d_in[6];  pa.Wt[1] = wtao;   pa.cn[1] = c_ao;   pa.N[1] = 768;
  pa.W[2] = (const float*)d_in[10]; pa.Wt[2] = wtfc;   pa.cn[2] = c_fc;   pa.N[2] = 3072;
  pa.W[3] = (const float*)d_in[13]; pa.Wt[3] = wtgate; pa.cn[3] = c_gate; pa.N[3] = 3072;
  pa.W[4] = (const float*)d_in[16]; pa.Wt[4] = wtproj; pa.cn[4] = c_proj; pa.N[4] = 768;
  pa.off[0] = 0; pa.off[1] = 1728; pa.off[2] = 2304; pa.off[3] = 4608;
  pa.off[4] = 6912; pa.off[5] = 9216;
  pa.x = xin; pa.g1s = (const float*)d_in[2]; pa.h1 = h1; pa.hrow1 = hrow1;
  k_prep<<<11520, 256, 0, stream>>>(pa);

  GemmArgs gq = {};
  gq.A = h1; gq.Bt = wtqkv; gq.arow2 = hrow1; gq.wcol2 = c_qkv;
  gq.bias = (const float*)d_in[4]; gq.alpha = (const float*)d_in[5];
  gq.N = 2304; gq.ks = 768;
  gq.rope = rope; gq.qo = qbuf; gq.ko = kbuf; gq.vo = vbuf;
  k_gemm<M_QKV, 24, 32, 18, 1><<<576, 256, 0, stream>>>(gq);

  k_attn<<<1536, 64, 0, stream>>>(qbuf, kbuf, vbuf, obuf, orow2);

  GemmArgs ga = {};
  ga.A = obuf; ga.Bt = wtao; ga.arow2 = orow2; ga.wcol2 = c_ao;
  ga.bias = (const float*)d_in[7]; ga.alpha = (const float*)d_in[8];
  ga.N = 768; ga.ks = 768;
  ga.xf = xin; ga.xo = xo;
  k_gemm<M_AO, 24, 32, 6, 1><<<192, 256, 0, stream>>>(ga);

  k_ln<<<2048, 256, 0, stream>>>(xo, (const float*)d_in[9], h2, hrow2);

  MlpArgs gm = {};
  gm.A = h2; gm.Bf = wtfc; gm.Bg = wtgate; gm.arow2 = hrow2;
  gm.w2f = c_fc; gm.w2g = c_gate;
  gm.bf = (const float*)d_in[11]; gm.bg = (const float*)d_in[14];
  gm.af_ = (const float*)d_in[12]; gm.ag_ = (const float*)d_in[15];
  gm.mlp = mlp; gm.mrow2 = mrow2;
  k_mlp<<<768, 256, 0, stream>>>(gm);

  GemmArgs gp = {};
  gp.A = mlp; gp.Bt = wtproj;
  gp.N = 768; gp.ks = 3072;
  gp.partb = slabs;
  k_gemm<M_PART, 24, 32, 6, 4><<<768, 256, 0, stream>>>(gp);

  EpiArgs ge = {};
  ge.slab = slabs; ge.arow2 = mrow2; ge.wcol2 = c_proj;
  ge.bias = (const float*)d_in[17]; ge.alpha = (const float*)d_in[18];
  ge.xo = xo; ge.outf = (float*)d_out;
  k_proj_epi<<<1536, 256, 0, stream>>>(ge);
}

// Round 7
// 270.850 us; speedup vs baseline: 1.0357x; 1.0357x over previous
//
#include <hip/hip_runtime.h>
#include <cstdint>

#define DEVFN static __device__ __forceinline__

typedef __bf16 bf16x8 __attribute__((ext_vector_type(8)));
typedef float f32x4 __attribute__((ext_vector_type(4)));
typedef unsigned short us4 __attribute__((ext_vector_type(4)));

DEVFN unsigned short f2bf(float f) {
  unsigned u = __float_as_uint(f);
  u += 0x7fffu + ((u >> 16) & 1u);           // round-to-nearest-even
  return (unsigned short)(u >> 16);
}
DEVFN float bf2f(unsigned short h) { return __uint_as_float(((unsigned)h) << 16); }
DEVFN void async16(const void* g, void* l) {
  __builtin_amdgcn_global_load_lds((__attribute__((address_space(1))) const void*)g,
                                   (__attribute__((address_space(3))) void*)l, 16, 0, 0);
}
// gelu(tanh approx) == u * sigmoid(2z), z = 0.79788456*(u+0.044715u^3)  (exact identity)
DEVFN float gelu_t(float u) {
  float z = 0.7978845608028654f * (u + 0.044715f * u * u * u);
  float zc = fminf(fmaxf(z, -15.f), 15.f);
  float e = __expf(2.f * zc);
  return u * __fdividef(e, e + 1.f);
}
// XCD swizzle: lin%8 = XCD class; give each XCD a contiguous slice of g-space
DEVFN int xcd_swizzle(int lin, int total) {
  return (lin & 7) * (total >> 3) + (lin >> 3);
}

// ---------------- merged prep: rope + 5 transposes + LN1 --------------------
struct PrepArgs {
  float* rope;
  const float* W[5]; unsigned short* Wt[5]; float* cn[5];
  int N[5]; int off[6];
  const float* x; const float* g1s; unsigned short* h1; float* hrow1;
};
__global__ __launch_bounds__(256) void k_prep(PrepArgs a) {
  __shared__ float tile[32][33];
  __shared__ float part[8][32];
  __shared__ float red[12];
  const int bid = blockIdx.x, tid = threadIdx.x;
  if (bid < 256) {                       // rope table
    int g = bid * 256 + tid;
    int t = g >> 6, dd = g & 63, i = dd & 31;
    float fr = __expf(-0.2878231366242558f * (float)i);   // ln(1e4)/32
    float ang = (float)t * fr;
    a.rope[g] = (dd < 32) ? cosf(ang) : sinf(ang);
  } else if (bid < 9472) {               // weight transpose + col sq-norms
    int lin = bid - 256;
    int e = 0;
    while (lin >= a.off[e + 1]) ++e;
    int local = lin - a.off[e];
    const int N = a.N[e];
    int nbx = N >> 5;
    int tn = local % nbx, tk = local / nbx;
    const float* W = a.W[e];
    unsigned short* Wt = a.Wt[e];
    float* cn = a.cn[e];
    const int K = (e == 4) ? 3072 : 768;
    int tx = tid & 31, ty = tid >> 5;
    float acc = 0.f;
    #pragma unroll
    for (int j = 0; j < 4; ++j) {
      int r = ty + j * 8;
      float v = W[(long)(tk * 32 + r) * N + tn * 32 + tx];
      tile[r][tx] = v;
      acc += v * v;
    }
    part[ty][tx] = acc;
    __syncthreads();
    #pragma unroll
    for (int j = 0; j < 4; ++j) {
      int rr = ty + j * 8;
      Wt[(long)(tn * 32 + rr) * K + tk * 32 + tx] = f2bf(tile[tx][rr]);
    }
    if (ty == 0) {
      float s = part[0][tx];
      #pragma unroll
      for (int jj = 1; jj < 8; ++jj) s += part[jj][tx];
      atomicAdd(&cn[tn * 32 + tx], s);
    }
  } else {                               // LN1
    int row = bid - 9472;
    const float* xr = a.x + (long)row * 768;
    float v0 = xr[tid], v1 = xr[tid + 256], v2 = xr[tid + 512];
    float s = v0 + v1 + v2;
    float ss = v0 * v0 + v1 * v1 + v2 * v2;
    #pragma unroll
    for (int o = 32; o; o >>= 1) { s += __shfl_xor(s, o); ss += __shfl_xor(ss, o); }
    int wv = tid >> 6;
    if ((tid & 63) == 0) { red[wv] = s; red[wv + 4] = ss; }
    __syncthreads();
    s = red[0] + red[1] + red[2] + red[3];
    ss = red[4] + red[5] + red[6] + red[7];
    float mu = s * (1.f / 768.f);
    float var = ss * (1.f / 768.f) - mu * mu;
    float rs = rsqrtf(var + 1e-6f);
    float h0 = (v0 - mu) * rs * a.g1s[tid];
    float h1 = (v1 - mu) * rs * a.g1s[tid + 256];
    float h2 = (v2 - mu) * rs * a.g1s[tid + 512];
    unsigned short* hr = a.h1 + (long)row * 768;
    hr[tid] = f2bf(h0); hr[tid + 256] = f2bf(h1); hr[tid + 512] = f2bf(h2);
    float p = h0 * h0 + h1 * h1 + h2 * h2;
    #pragma unroll
    for (int o = 32; o; o >>= 1) p += __shfl_xor(p, o);
    if ((tid & 63) == 0) red[8 + wv] = p;
    __syncthreads();
    if (tid == 0) a.hrow1[row] = red[8] + red[9] + red[10] + red[11];
  }
}

// ---------------- layernorm (f32 in) -> bf16 h + row sum(h^2) ---------------
__global__ __launch_bounds__(256) void k_ln(const float* __restrict__ x,
    const float* __restrict__ g, unsigned short* __restrict__ h, float* __restrict__ row2) {
  int row = blockIdx.x, tid = threadIdx.x;
  const float* xr = x + (long)row * 768;
  float v0 = xr[tid], v1 = xr[tid + 256], v2 = xr[tid + 512];
  float s = v0 + v1 + v2;
  float ss = v0 * v0 + v1 * v1 + v2 * v2;
  #pragma unroll
  for (int o = 32; o; o >>= 1) { s += __shfl_xor(s, o); ss += __shfl_xor(ss, o); }
  __shared__ float red[12];
  int wv = tid >> 6;
  if ((tid & 63) == 0) { red[wv] = s; red[wv + 4] = ss; }
  __syncthreads();
  s = red[0] + red[1] + red[2] + red[3];
  ss = red[4] + red[5] + red[6] + red[7];
  float mu = s * (1.f / 768.f);
  float var = ss * (1.f / 768.f) - mu * mu;
  float rs = rsqrtf(var + 1e-6f);
  float h0 = (v0 - mu) * rs * g[tid];
  float h1 = (v1 - mu) * rs * g[tid + 256];
  float h2 = (v2 - mu) * rs * g[tid + 512];
  unsigned short* hr = h + (long)row * 768;
  hr[tid] = f2bf(h0); hr[tid + 256] = f2bf(h1); hr[tid + 512] = f2bf(h2);
  float p = h0 * h0 + h1 * h1 + h2 * h2;
  #pragma unroll
  for (int o = 32; o; o >>= 1) p += __shfl_xor(p, o);
  if ((tid & 63) == 0) red[8 + wv] = p;
  __syncthreads();
  if (tid == 0) row2[row] = red[8] + red[9] + red[10] + red[11];
}

// ---------------- yat GEMM: 64x128 tile, 3-buffer distance-2, XCD swizzle ---
constexpr int M_QKV = 0, M_AO = 1, M_PART = 2;

struct GemmArgs {
  const unsigned short* A; const unsigned short* Bt;
  const float* arow2; const float* wcol2; const float* bias; const float* alpha;
  int N; int ks;
  const float* rope;                                    // QKV
  unsigned short* qo; unsigned short* ko; unsigned short* vo;  // QKV
  const float* xf; float* xo;                           // AO: residual in/out (f32)
  unsigned short* partb;                                // PART: bf16 slab base
};

template <int MODE, int NI, int NBM, int NBN, int NZ>
__global__ __launch_bounds__(256, 4) void k_gemm(GemmArgs p) {
  __shared__ __align__(16) unsigned short As[3][2048];   // 64 x 32
  __shared__ __align__(16) unsigned short Bs[3][4096];   // 128 x 32
  const int tid = threadIdx.x, wave = tid >> 6, lane = tid & 63;
  const int quad = lane >> 4, l = lane & 15;
  constexpr int TOTAL = NBM * NBN * NZ;
  const int g = xcd_swizzle(blockIdx.x, TOTAL);
  const int bm = (g % NBM) * 64;
  const int rest = g / NBM;
  const int bn = (rest % NBN) * 128;
  const int z = rest / NBN;
  const int kb = z * (NI * 32);
  const int ks = p.ks;
  const int wm = (wave & 1) * 32, wn = (wave >> 1) * 64;
  const f32x4 fzero = {0.f, 0.f, 0.f, 0.f};
  f32x4 acc[2][4];
  #pragma unroll
  for (int i = 0; i < 2; ++i)
    #pragma unroll
    for (int j = 0; j < 4; ++j) acc[i][j] = fzero;
  const int sw = (l >> 1) & 3;

  // hoisted per-thread staging pointers (advance +32 elements per stage call)
  const int r0 = tid >> 2;
  const int c0 = (tid & 3) ^ ((r0 >> 1) & 3);
  const unsigned short* ap  = p.A  + (long)(bm + r0) * ks + kb + c0 * 8;
  const unsigned short* bp0 = p.Bt + (long)(bn + r0) * ks + kb + c0 * 8;
  const unsigned short* bp1 = bp0 + (long)64 * ks;

  auto stage = [&](int s) {
    async16(ap,  &As[s][tid * 8]);
    async16(bp0, &Bs[s][tid * 8]);
    async16(bp1, &Bs[s][(tid + 256) * 8]);
    ap += 32; bp0 += 32; bp1 += 32;
  };
  auto compute = [&](int s) {
    bf16x8 af[2], bfv[4];
    #pragma unroll
    for (int mi = 0; mi < 2; ++mi)
      af[mi] = *(const bf16x8*)&As[s][(wm + mi * 16 + l) * 32 + ((quad ^ sw) * 8)];
    #pragma unroll
    for (int ni = 0; ni < 4; ++ni)
      bfv[ni] = *(const bf16x8*)&Bs[s][(wn + ni * 16 + l) * 32 + ((quad ^ sw) * 8)];
    #pragma unroll
    for (int mi = 0; mi < 2; ++mi)
      #pragma unroll
      for (int ni = 0; ni < 4; ++ni)
        acc[mi][ni] = __builtin_amdgcn_mfma_f32_16x16x32_bf16(af[mi], bfv[ni], acc[mi][ni], 0, 0, 0);
  };
  auto iter = [&](int s, int i) {
    if (i + 1 >= NI) { asm volatile("s_waitcnt vmcnt(0)" ::: "memory"); }
    else             { asm volatile("s_waitcnt vmcnt(3)" ::: "memory"); }
    __builtin_amdgcn_s_barrier();
    asm volatile("" ::: "memory");
    if (i + 2 < NI) stage(s == 0 ? 2 : s - 1);
    compute(s);
  };

  stage(0);
  stage(1);
  int i = 0;
  while (i < NI) {          // NI % 3 == 0
    iter(0, i); ++i;
    iter(1, i); ++i;
    iter(2, i); ++i;
  }

  if constexpr (MODE == M_PART) {
    unsigned short* slab = p.partb + (long)z * (2048 * 768);
    #pragma unroll
    for (int ni = 0; ni < 4; ++ni) {
      const int j = bn + wn + ni * 16 + l;
      #pragma unroll
      for (int mi = 0; mi < 2; ++mi) {
        const int i0 = bm + wm + mi * 16 + quad * 4;
        #pragma unroll
        for (int rg = 0; rg < 4; ++rg)
          slab[(long)(i0 + rg) * 768 + j] = f2bf(acc[mi][ni][rg]);
      }
    }
  } else {
    const float al = p.alpha[0];
    const float nn = (float)p.N;
    const float ys = powf(sqrtf(nn) / log1pf(nn), al);
    #pragma unroll
    for (int ni = 0; ni < 4; ++ni) {
      const int j = bn + wn + ni * 16 + l;
      const float w2 = p.wcol2[j];
      const float bj = p.bias[j];
      int s3 = 0, hh = 0, dd = 0;
      if constexpr (MODE == M_QKV) { s3 = j / 768; int rem = j - s3 * 768; hh = rem >> 6; dd = rem & 63; }
      #pragma unroll
      for (int mi = 0; mi < 2; ++mi) {
        const int i0 = bm + wm + mi * 16 + quad * 4;
        float vv[4];
        #pragma unroll
        for (int rg = 0; rg < 4; ++rg) {
          const float y = acc[mi][ni][rg];
          const float dist = p.arow2[i0 + rg] + w2 - 2.f * y + 1e-6f;
          vv[rg] = (__fdividef(y * y, dist) + bj) * ys;
        }
        if constexpr (MODE == M_QKV) {
          int b = i0 >> 10, t0 = i0 & 1023;
          if (s3 == 2) {
            us4 pk = {f2bf(vv[0]), f2bf(vv[1]), f2bf(vv[2]), f2bf(vv[3])};
            *(us4*)&p.vo[((long)(b * 12 + hh) * 64 + dd) * 1024 + t0] = pk;    // V^T (B,H,D,T)
          } else {
            unsigned short* dst = (s3 == 0) ? p.qo : p.ko;                     // (B,H,T,D)
            #pragma unroll
            for (int rg = 0; rg < 4; ++rg) {
              float ro = p.rope[(t0 + rg) * 64 + dd];
              dst[((long)(b * 12 + hh) * 1024 + t0 + rg) * 64 + dd] = f2bf(vv[rg] * ro);
            }
          }
        } else {  // M_AO
          #pragma unroll
          for (int rg = 0; rg < 4; ++rg) {
            long idx = (long)(i0 + rg) * 768 + j;
            p.xo[idx] = p.xf[idx] + vv[rg];
          }
        }
      }
    }
  }
}

// ---------------- PROJ reduce (4 bf16 slabs) + yat epilogue + residual ------
struct EpiArgs {
  const unsigned short* slab; const float* arow2; const float* wcol2;
  const float* bias; const float* alpha; const float* xo; float* outf;
};
__global__ __launch_bounds__(256) void k_proj_epi(EpiArgs p) {
  int g = blockIdx.x * 256 + threadIdx.x;   // 393216 = 2048*768/4
  int i = g / 192, jv = (g - i * 192) * 4;
  long base = (long)i * 768 + jv;
  f32x4 y = {0.f, 0.f, 0.f, 0.f};
  #pragma unroll
  for (int z = 0; z < 4; ++z) {
    us4 s4 = *(const us4*)(p.slab + (long)z * 1572864 + base);
    #pragma unroll
    for (int c = 0; c < 4; ++c) y[c] += bf2f(s4[c]);
  }
  const float a2 = p.arow2[i];
  const float ys = powf(sqrtf(768.f) / log1pf(768.f), p.alpha[0]);
  f32x4 xo4 = *(const f32x4*)(p.xo + base);
  f32x4 out;
  #pragma unroll
  for (int c = 0; c < 4; ++c) {
    float yy = y[c];
    float dist = a2 + p.wcol2[jv + c] - 2.f * yy + 1e-6f;
    out[c] = xo4[c] + (__fdividef(yy * yy, dist) + p.bias[jv + c]) * ys;
  }
  *(f32x4*)(p.outf + base) = out;
}

// ---- merged FC+GATE yat GEMM: 128x64 tile, A+B all LDS-staged, 3-buffer ----
// (R4 best-measured version: 43.6 us. Structure-limited; frozen.)
struct MlpArgs {
  const unsigned short* A; const unsigned short* Bf; const unsigned short* Bg;
  const float* arow2; const float* w2f; const float* w2g;
  const float* bf; const float* bg; const float* af_; const float* ag_;
  unsigned short* mlp; float* mrow2;
};

__global__ __launch_bounds__(256, 3) void k_mlp(MlpArgs p) {
  constexpr int NI = 24, K = 768;
  __shared__ __align__(16) unsigned short As[3][4096];    // 128 x 32
  __shared__ __align__(16) unsigned short Bfs[3][2048];   // 64 x 32
  __shared__ __align__(16) unsigned short Bgs[3][2048];   // 64 x 32
  const int tid = threadIdx.x, wave = tid >> 6, lane = tid & 63;
  const int quad = lane >> 4, l = lane & 15;
  const int g = xcd_swizzle(blockIdx.x, 16 * 48);
  const int bm = (g % 16) * 128, bn = (g / 16) * 64;
  const int wm = wave * 32;                // 4 waves x 32 rows; all share 64 cols
  const f32x4 fzero = {0.f, 0.f, 0.f, 0.f};
  f32x4 accf[2][4], accg[2][4];
  #pragma unroll
  for (int i = 0; i < 2; ++i)
    #pragma unroll
    for (int j = 0; j < 4; ++j) { accf[i][j] = fzero; accg[i][j] = fzero; }
  const int sw = (l >> 1) & 3;

  // hoisted per-thread staging pointers (advance +32 elements per stage call)
  const int r0 = tid >> 2;
  const int c0 = (tid & 3) ^ ((r0 >> 1) & 3);
  const unsigned short* ap0 = p.A  + (long)(bm + r0) * K + c0 * 8;
  const unsigned short* ap1 = ap0 + (long)64 * K;
  const unsigned short* bfp = p.Bf + (long)(bn + r0) * K + c0 * 8;
  const unsigned short* bgp = p.Bg + (long)(bn + r0) * K + c0 * 8;

  auto stage = [&](int s) {
    async16(ap0, &As[s][tid * 8]);
    async16(ap1, &As[s][(tid + 256) * 8]);
    async16(bfp, &Bfs[s][tid * 8]);
    async16(bgp, &Bgs[s][tid * 8]);
    ap0 += 32; ap1 += 32; bfp += 32; bgp += 32;
  };
  auto compute = [&](int s) {
    bf16x8 af[2], bff[4], bfg[4];
    #pragma unroll
    for (int mi = 0; mi < 2; ++mi)
      af[mi] = *(const bf16x8*)&As[s][(wm + mi * 16 + l) * 32 + ((quad ^ sw) * 8)];
    #pragma unroll
    for (int ni = 0; ni < 4; ++ni) {
      bff[ni] = *(const bf16x8*)&Bfs[s][(ni * 16 + l) * 32 + ((quad ^ sw) * 8)];
      bfg[ni] = *(const bf16x8*)&Bgs[s][(ni * 16 + l) * 32 + ((quad ^ sw) * 8)];
    }
    __builtin_amdgcn_s_setprio(1);
    #pragma unroll
    for (int ni = 0; ni < 4; ++ni) {
      accf[0][ni] = __builtin_amdgcn_mfma_f32_16x16x32_bf16(af[0], bff[ni], accf[0][ni], 0, 0, 0);
      accg[0][ni] = __builtin_amdgcn_mfma_f32_16x16x32_bf16(af[0], bfg[ni], accg[0][ni], 0, 0, 0);
      accf[1][ni] = __builtin_amdgcn_mfma_f32_16x16x32_bf16(af[1], bff[ni], accf[1][ni], 0, 0, 0);
      accg[1][ni] = __builtin_amdgcn_mfma_f32_16x16x32_bf16(af[1], bfg[ni], accg[1][ni], 0, 0, 0);
    }
    __builtin_amdgcn_s_setprio(0);
  };
  auto iter = [&](int s, int i) {
    if (i + 1 >= NI) { asm volatile("s_waitcnt vmcnt(0)" ::: "memory"); }
    else             { asm volatile("s_waitcnt vmcnt(4)" ::: "memory"); }
    __builtin_amdgcn_s_barrier();
    asm volatile("" ::: "memory");
    if (i + 2 < NI) stage((i + 2) % 3);
    compute(s);
  };

  stage(0);
  stage(1);
  int i = 0;
  while (i < NI) {          // NI % 3 == 0
    iter(0, i); ++i;
    iter(1, i); ++i;
    iter(2, i); ++i;
  }

  const float ysf = powf(sqrtf(3072.f) / log1pf(3072.f), p.af_[0]);
  const float ysg = powf(sqrtf(3072.f) / log1pf(3072.f), p.ag_[0]);
  float w2f[4], w2g[4], bjf[4], bjg[4]; int js[4];
  #pragma unroll
  for (int ni = 0; ni < 4; ++ni) {
    int j = bn + ni * 16 + l;
    js[ni] = j; w2f[ni] = p.w2f[j]; w2g[ni] = p.w2g[j]; bjf[ni] = p.bf[j]; bjg[ni] = p.bg[j];
  }
  #pragma unroll
  for (int mi = 0; mi < 2; ++mi) {
    #pragma unroll
    for (int rg = 0; rg < 4; ++rg) {
      const int ii = bm + wm + mi * 16 + quad * 4 + rg;
      const float a2 = p.arow2[ii];
      float rsum = 0.f;
      #pragma unroll
      for (int ni = 0; ni < 4; ++ni) {
        float yf = accf[mi][ni][rg];
        float gate = (__fdividef(yf * yf, a2 + w2f[ni] - 2.f * yf + 1e-6f) + bjf[ni]) * ysf;
        float yg = accg[mi][ni][rg];
        float u  = (__fdividef(yg * yg, a2 + w2g[ni] - 2.f * yg + 1e-6f) + bjg[ni]) * ysg;
        float out = gelu_t(u) * gate;
        p.mlp[(long)ii * 3072 + js[ni]] = f2bf(out);
        rsum += out * out;
      }
      #pragma unroll
      for (int o = 8; o; o >>= 1) rsum += __shfl_xor(rsum, o);
      if (l == 0) atomicAdd(&p.mrow2[ii], rsum);
    }
  }
}

// ---------------- flash attention: 64-row Q tiles, K staged, V direct -------
// R7 hybrid: restore the proven 4-wave dist-2 K staging (R6's 1-wave rewrite
// was latency-exposed: 2.5% MfmaUtil, 8% occupancy). Keep R6's one validated
// piece: V^T fragments loaded direct global->VGPR right after the barrier,
// consumed only in PV -- the softmax VALU chain covers their L2 latency.
// Drops Vs LDS (64->40KB) and halves async16 count per tile; vmcnt 4->2.
__global__ __launch_bounds__(256) void k_attn(const unsigned short* __restrict__ qb,
    const unsigned short* __restrict__ kb, const unsigned short* __restrict__ vb,
    unsigned short* __restrict__ ob, float* __restrict__ orow2) {
  __shared__ __align__(16) unsigned short Qs[4096];
  __shared__ __align__(16) unsigned short Ks[3][4096];
  __shared__ __align__(16) unsigned short Ps[4096];
  const int tid = threadIdx.x, wave = tid >> 6, lane = tid & 63;
  const int quad = lane >> 4, l = lane & 15;
  const int g = xcd_swizzle(blockIdx.x, 16 * 24);
  const int bh = g % 24, qt = 15 - (g / 24);   // heavy q-tiles first
  const int b = bh / 12, hh = bh % 12;
  const int q0 = qt * 64;
  const f32x4 fzero = {0.f, 0.f, 0.f, 0.f};

  // hoisted K staging pointers (2 async16/thread per tile)
  const int rkv = tid >> 3;                       // 0..31
  const int ckv = (tid & 7) ^ (rkv & 7);
  const unsigned short* kp0 = kb + ((long)bh * 1024 + rkv) * 64 + ckv * 8;
  const unsigned short* kp1 = kp0 + (long)32 * 64;

  auto stage_k = [&](int s) {
    async16(kp0, &Ks[s][tid * 8]);
    async16(kp1, &Ks[s][(tid + 256) * 8]);
    kp0 += 4096; kp1 += 4096;    // next 64 K-rows
  };

  // V^T direct per-lane fragment pointer (mapping validated in R6)
  const unsigned short* vpd = vb + (long)bh * 65536 + (long)l * 1024 + quad * 8;

  const unsigned short* qg = qb + ((long)bh * 1024 + q0) * 64;
  #pragma unroll
  for (int it = 0; it < 2; ++it) {
    int ci = tid + it * 256;
    int r = ci >> 3;
    int c = (ci & 7) ^ (r & 7);
    async16(qg + (long)r * 64 + c * 8, &Qs[ci * 8]);
  }
  stage_k(0);
  if (qt >= 1) {
    stage_k(1);
    asm volatile("s_waitcnt vmcnt(2)" ::: "memory");   // Q + stage0 done
  } else {
    asm volatile("s_waitcnt vmcnt(0)" ::: "memory");
  }
  __builtin_amdgcn_s_barrier();
  asm volatile("" ::: "memory");

  bf16x8 aq[2];
  #pragma unroll
  for (int ks = 0; ks < 2; ++ks)
    aq[ks] = *(const bf16x8*)&Qs[(wave * 16 + l) * 64 + (((ks * 4 + quad) ^ (l & 7)) * 8)];

  f32x4 O[4];
  float mi_[4], li[4];
  #pragma unroll
  for (int f = 0; f < 4; ++f) O[f] = fzero;
  #pragma unroll
  for (int r = 0; r < 4; ++r) { mi_[r] = -1e30f; li[r] = 0.f; }

  for (int jt = 0; jt <= qt; ++jt) {
    const int s = jt % 3;
    if (jt > 0) {
      if (jt + 1 <= qt) { asm volatile("s_waitcnt vmcnt(2)" ::: "memory"); }
      else              { asm volatile("s_waitcnt vmcnt(0)" ::: "memory"); }
      __builtin_amdgcn_s_barrier();
      asm volatile("" ::: "memory");
    }
    if (jt + 2 <= qt) stage_k((jt + 2) % 3);

    // issue V fragment loads now; first use is PV (after softmax) -> latency hidden
    bf16x8 bv[2][4];
    #pragma unroll
    for (int f = 0; f < 4; ++f)
      #pragma unroll
      for (int ks = 0; ks < 2; ++ks)
        bv[ks][f] = *(const bf16x8*)(vpd + f * 16384 + ks * 32);
    vpd += 64;     // next 64 t-columns

    f32x4 S[4];
    #pragma unroll
    for (int f = 0; f < 4; ++f) S[f] = fzero;
    #pragma unroll
    for (int ks = 0; ks < 2; ++ks) {
      #pragma unroll
      for (int f = 0; f < 4; ++f) {
        bf16x8 bk = *(const bf16x8*)&Ks[s][(f * 16 + l) * 64 + (((ks * 4 + quad) ^ (l & 7)) * 8)];
        S[f] = __builtin_amdgcn_mfma_f32_16x16x32_bf16(aq[ks], bk, S[f], 0, 0, 0);
      }
    }
    const bool diag = (jt == qt);
    #pragma unroll
    for (int f = 0; f < 4; ++f)
      #pragma unroll
      for (int r = 0; r < 4; ++r) {
        float v = S[f][r] * 0.125f;
        if (diag && (f * 16 + l > wave * 16 + quad * 4 + r)) v = -1e30f;
        S[f][r] = v;
      }
    #pragma unroll
    for (int r = 0; r < 4; ++r) {
      float mx = fmaxf(fmaxf(S[0][r], S[1][r]), fmaxf(S[2][r], S[3][r]));
      #pragma unroll
      for (int o = 8; o; o >>= 1) mx = fmaxf(mx, __shfl_xor(mx, o));
      float mnew = fmaxf(mi_[r], mx);
      float alr = __expf(mi_[r] - mnew);
      float sum = 0.f;
      #pragma unroll
      for (int f = 0; f < 4; ++f) {
        float e = __expf(S[f][r] - mnew);
        S[f][r] = e;
        sum += e;
      }
      #pragma unroll
      for (int o = 8; o; o >>= 1) sum += __shfl_xor(sum, o);
      li[r] = li[r] * alr + sum;
      #pragma unroll
      for (int f = 0; f < 4; ++f) O[f][r] *= alr;
      mi_[r] = mnew;
    }
    #pragma unroll
    for (int f = 0; f < 4; ++f)
      #pragma unroll
      for (int r = 0; r < 4; ++r) {
        int i = quad * 4 + r;
        int j = f * 16 + l;
        int pch = (j >> 3) ^ (i & 7);
        Ps[wave * 1024 + i * 64 + pch * 8 + (j & 7)] = f2bf(S[f][r]);
      }
    #pragma unroll
    for (int ks = 0; ks < 2; ++ks) {
      bf16x8 ap = *(const bf16x8*)&Ps[wave * 1024 + l * 64 + (((ks * 4 + quad) ^ (l & 7)) * 8)];
      #pragma unroll
      for (int f = 0; f < 4; ++f)
        O[f] = __builtin_amdgcn_mfma_f32_16x16x32_bf16(ap, bv[ks][f], O[f], 0, 0, 0);
    }
  }
  float inv[4];
  #pragma unroll
  for (int r = 0; r < 4; ++r) inv[r] = __fdividef(1.f, li[r]);
  #pragma unroll
  for (int f = 0; f < 4; ++f)
    #pragma unroll
    for (int r = 0; r < 4; ++r) {
      int t = q0 + wave * 16 + quad * 4 + r;
      int dd = f * 16 + l;
      ob[((long)(b * 1024 + t) * 12 + hh) * 64 + dd] = f2bf(O[f][r] * inv[r]);  // (B,T,H,D)
    }
  #pragma unroll
  for (int r = 0; r < 4; ++r) {
    float rsum = 0.f;
    #pragma unroll
    for (int f = 0; f < 4; ++f) { float v = O[f][r] * inv[r]; rsum += v * v; }
    #pragma unroll
    for (int o = 8; o; o >>= 1) rsum += __shfl_xor(rsum, o);
    if (l == 0) {
      int t = q0 + wave * 16 + quad * 4 + r;
      atomicAdd(&orow2[b * 1024 + t], rsum);
    }
  }
}

// ---------------- host ------------------------------------------------------
extern "C" void kernel_launch(void* const* d_in, const int* in_sizes, int n_in,
                              void* d_out, int out_size, void* d_ws, size_t ws_size,
                              hipStream_t stream) {
  (void)in_sizes; (void)n_in; (void)out_size;
  char* w = (char*)d_ws;
  size_t off = 0;
  auto alloc = [&](size_t bytes) -> void* {
    void* p = w + off;
    off = (off + bytes + 255) & ~(size_t)255;
    return p;
  };
  float* rope            = (float*)alloc(65536 * 4);
  unsigned short* wtqkv  = (unsigned short*)alloc((size_t)2304 * 768 * 2);
  unsigned short* wtao   = (unsigned short*)alloc((size_t)768 * 768 * 2);
  unsigned short* wtfc   = (unsigned short*)alloc((size_t)3072 * 768 * 2);
  unsigned short* wtgate = (unsigned short*)alloc((size_t)3072 * 768 * 2);
  unsigned short* wtproj = (unsigned short*)alloc((size_t)768 * 3072 * 2);
  float* zeroed          = (float*)alloc(14080 * 4);   // wcol2(9984) + orow2(2048) + mrow2(2048)
  unsigned short* h1     = (unsigned short*)alloc((size_t)2048 * 768 * 2);
  float* hrow1           = (float*)alloc(2048 * 4);
  unsigned short* qbuf   = (unsigned short*)alloc((size_t)2048 * 768 * 2);
  unsigned short* kbuf   = (unsigned short*)alloc((size_t)2048 * 768 * 2);
  unsigned short* vbuf   = (unsigned short*)alloc((size_t)2048 * 768 * 2);
  unsigned short* obuf   = (unsigned short*)alloc((size_t)2048 * 768 * 2);
  float* xo              = (float*)alloc((size_t)2048 * 768 * 4);
  unsigned short* h2     = (unsigned short*)alloc((size_t)2048 * 768 * 2);
  float* hrow2           = (float*)alloc(2048 * 4);
  unsigned short* mlp    = (unsigned short*)alloc((size_t)2048 * 3072 * 2);
  unsigned short* slabs  = (unsigned short*)alloc((size_t)4 * 2048 * 768 * 2);  // bf16 split-K partials
  if (off > ws_size) return;

  float* wcol2  = zeroed;
  float* orow2  = zeroed + 9984;
  float* mrow2  = zeroed + 9984 + 2048;
  float* c_qkv  = wcol2 + 0;
  float* c_ao   = wcol2 + 2304;
  float* c_fc   = wcol2 + 3072;
  float* c_gate = wcol2 + 6144;
  float* c_proj = wcol2 + 9216;

  const float* xin = (const float*)d_in[0];

  hipMemsetAsync(zeroed, 0, 14080 * 4, stream);

  PrepArgs pa;
  pa.rope = rope;
  pa.W[0] = (const float*)d_in[3];  pa.Wt[0] = wtqkv;  pa.cn[0] = c_qkv;  pa.N[0] = 2304;
  pa.W[1] = (const float*)d_in[6];  pa.Wt[1] = wtao;   pa.cn[1] = c_ao;   pa.N[1] = 768;
  pa.W[2] = (const float*)d_in[10]; pa.Wt[2] = wtfc;   pa.cn[2] = c_fc;   pa.N[2] = 3072;
  pa.W[3] = (const float*)d_in[13]; pa.Wt[3] = wtgate; pa.cn[3] = c_gate; pa.N[3] = 3072;
  pa.W[4] = (const float*)d_in[16]; pa.Wt[4] = wtproj; pa.cn[4] = c_proj; pa.N[4] = 768;
  pa.off[0] = 0; pa.off[1] = 1728; pa.off[2] = 2304; pa.off[3] = 4608;
  pa.off[4] = 6912; pa.off[5] = 9216;
  pa.x = xin; pa.g1s = (const float*)d_in[2]; pa.h1 = h1; pa.hrow1 = hrow1;
  k_prep<<<11520, 256, 0, stream>>>(pa);

  GemmArgs gq = {};
  gq.A = h1; gq.Bt = wtqkv; gq.arow2 = hrow1; gq.wcol2 = c_qkv;
  gq.bias = (const float*)d_in[4]; gq.alpha = (const float*)d_in[5];
  gq.N = 2304; gq.ks = 768;
  gq.rope = rope; gq.qo = qbuf; gq.ko = kbuf; gq.vo = vbuf;
  k_gemm<M_QKV, 24, 32, 18, 1><<<576, 256, 0, stream>>>(gq);

  k_attn<<<384, 256, 0, stream>>>(qbuf, kbuf, vbuf, obuf, orow2);

  GemmArgs ga = {};
  ga.A = obuf; ga.Bt = wtao; ga.arow2 = orow2; ga.wcol2 = c_ao;
  ga.bias = (const float*)d_in[7]; ga.alpha = (const float*)d_in[8];
  ga.N = 768; ga.ks = 768;
  ga.xf = xin; ga.xo = xo;
  k_gemm<M_AO, 24, 32, 6, 1><<<192, 256, 0, stream>>>(ga);

  k_ln<<<2048, 256, 0, stream>>>(xo, (const float*)d_in[9], h2, hrow2);

  MlpArgs gm = {};
  gm.A = h2; gm.Bf = wtfc; gm.Bg = wtgate; gm.arow2 = hrow2;
  gm.w2f = c_fc; gm.w2g = c_gate;
  gm.bf = (const float*)d_in[11]; gm.bg = (const float*)d_in[14];
  gm.af_ = (const float*)d_in[12]; gm.ag_ = (const float*)d_in[15];
  gm.mlp = mlp; gm.mrow2 = mrow2;
  k_mlp<<<768, 256, 0, stream>>>(gm);

  GemmArgs gp = {};
  gp.A = mlp; gp.Bt = wtproj;
  gp.N = 768; gp.ks = 3072;
  gp.partb = slabs;
  k_gemm<M_PART, 24, 32, 6, 4><<<768, 256, 0, stream>>>(gp);

  EpiArgs ge = {};
  ge.slab = slabs; ge.arow2 = mrow2; ge.wcol2 = c_proj;
  ge.bias = (const float*)d_in[17]; ge.alpha = (const float*)d_in[18];
  ge.xo = xo; ge.outf = (float*)d_out;
  k_proj_epi<<<1536, 256, 0, stream>>>(ge);
}

// Round 9
// 263.350 us; speedup vs baseline: 1.0652x; 1.0285x over previous
//
#include <hip/hip_runtime.h>
#include <cstdint>

#define DEVFN static __device__ __forceinline__

typedef __bf16 bf16x8 __attribute__((ext_vector_type(8)));
typedef float f32x4 __attribute__((ext_vector_type(4)));
typedef unsigned short us4 __attribute__((ext_vector_type(4)));

DEVFN unsigned short f2bf(float f) {
  unsigned u = __float_as_uint(f);
  u += 0x7fffu + ((u >> 16) & 1u);           // round-to-nearest-even
  return (unsigned short)(u >> 16);
}
DEVFN float bf2f(unsigned short h) { return __uint_as_float(((unsigned)h) << 16); }
DEVFN void async16(const void* g, void* l) {
  __builtin_amdgcn_global_load_lds((__attribute__((address_space(1))) const void*)g,
                                   (__attribute__((address_space(3))) void*)l, 16, 0, 0);
}
// gelu(tanh approx) == u * sigmoid(2z), z = 0.79788456*(u+0.044715u^3)  (exact identity)
DEVFN float gelu_t(float u) {
  float z = 0.7978845608028654f * (u + 0.044715f * u * u * u);
  float zc = fminf(fmaxf(z, -15.f), 15.f);
  float e = __expf(2.f * zc);
  return u * __fdividef(e, e + 1.f);
}
// XCD swizzle: lin%8 = XCD class; give each XCD a contiguous slice of g-space
DEVFN int xcd_swizzle(int lin, int total) {
  return (lin & 7) * (total >> 3) + (lin >> 3);
}

// ---------------- merged prep: rope + 5 transposes + LN1 --------------------
struct PrepArgs {
  float* rope;
  const float* W[5]; unsigned short* Wt[5]; float* cn[5];
  int N[5]; int off[6];
  const float* x; const float* g1s; unsigned short* h1; float* hrow1;
};
__global__ __launch_bounds__(256) void k_prep(PrepArgs a) {
  __shared__ float tile[32][33];
  __shared__ float part[8][32];
  __shared__ float red[12];
  const int bid = blockIdx.x, tid = threadIdx.x;
  if (bid < 256) {                       // rope table
    int g = bid * 256 + tid;
    int t = g >> 6, dd = g & 63, i = dd & 31;
    float fr = __expf(-0.2878231366242558f * (float)i);   // ln(1e4)/32
    float ang = (float)t * fr;
    a.rope[g] = (dd < 32) ? cosf(ang) : sinf(ang);
  } else if (bid < 9472) {               // weight transpose + col sq-norms
    int lin = bid - 256;
    int e = 0;
    while (lin >= a.off[e + 1]) ++e;
    int local = lin - a.off[e];
    const int N = a.N[e];
    int nbx = N >> 5;
    int tn = local % nbx, tk = local / nbx;
    const float* W = a.W[e];
    unsigned short* Wt = a.Wt[e];
    float* cn = a.cn[e];
    const int K = (e == 4) ? 3072 : 768;
    int tx = tid & 31, ty = tid >> 5;
    float acc = 0.f;
    #pragma unroll
    for (int j = 0; j < 4; ++j) {
      int r = ty + j * 8;
      float v = W[(long)(tk * 32 + r) * N + tn * 32 + tx];
      tile[r][tx] = v;
      acc += v * v;
    }
    part[ty][tx] = acc;
    __syncthreads();
    #pragma unroll
    for (int j = 0; j < 4; ++j) {
      int rr = ty + j * 8;
      Wt[(long)(tn * 32 + rr) * K + tk * 32 + tx] = f2bf(tile[tx][rr]);
    }
    if (ty == 0) {
      float s = part[0][tx];
      #pragma unroll
      for (int jj = 1; jj < 8; ++jj) s += part[jj][tx];
      atomicAdd(&cn[tn * 32 + tx], s);
    }
  } else {                               // LN1
    int row = bid - 9472;
    const float* xr = a.x + (long)row * 768;
    float v0 = xr[tid], v1 = xr[tid + 256], v2 = xr[tid + 512];
    float s = v0 + v1 + v2;
    float ss = v0 * v0 + v1 * v1 + v2 * v2;
    #pragma unroll
    for (int o = 32; o; o >>= 1) { s += __shfl_xor(s, o); ss += __shfl_xor(ss, o); }
    int wv = tid >> 6;
    if ((tid & 63) == 0) { red[wv] = s; red[wv + 4] = ss; }
    __syncthreads();
    s = red[0] + red[1] + red[2] + red[3];
    ss = red[4] + red[5] + red[6] + red[7];
    float mu = s * (1.f / 768.f);
    float var = ss * (1.f / 768.f) - mu * mu;
    float rs = rsqrtf(var + 1e-6f);
    float h0 = (v0 - mu) * rs * a.g1s[tid];
    float h1 = (v1 - mu) * rs * a.g1s[tid + 256];
    float h2 = (v2 - mu) * rs * a.g1s[tid + 512];
    unsigned short* hr = a.h1 + (long)row * 768;
    hr[tid] = f2bf(h0); hr[tid + 256] = f2bf(h1); hr[tid + 512] = f2bf(h2);
    float p = h0 * h0 + h1 * h1 + h2 * h2;
    #pragma unroll
    for (int o = 32; o; o >>= 1) p += __shfl_xor(p, o);
    if ((tid & 63) == 0) red[8 + wv] = p;
    __syncthreads();
    if (tid == 0) a.hrow1[row] = red[8] + red[9] + red[10] + red[11];
  }
}

// ---------------- layernorm (f32 in) -> bf16 h + row sum(h^2) ---------------
__global__ __launch_bounds__(256) void k_ln(const float* __restrict__ x,
    const float* __restrict__ g, unsigned short* __restrict__ h, float* __restrict__ row2) {
  int row = blockIdx.x, tid = threadIdx.x;
  const float* xr = x + (long)row * 768;
  float v0 = xr[tid], v1 = xr[tid + 256], v2 = xr[tid + 512];
  float s = v0 + v1 + v2;
  float ss = v0 * v0 + v1 * v1 + v2 * v2;
  #pragma unroll
  for (int o = 32; o; o >>= 1) { s += __shfl_xor(s, o); ss += __shfl_xor(ss, o); }
  __shared__ float red[12];
  int wv = tid >> 6;
  if ((tid & 63) == 0) { red[wv] = s; red[wv + 4] = ss; }
  __syncthreads();
  s = red[0] + red[1] + red[2] + red[3];
  ss = red[4] + red[5] + red[6] + red[7];
  float mu = s * (1.f / 768.f);
  float var = ss * (1.f / 768.f) - mu * mu;
  float rs = rsqrtf(var + 1e-6f);
  float h0 = (v0 - mu) * rs * g[tid];
  float h1 = (v1 - mu) * rs * g[tid + 256];
  float h2 = (v2 - mu) * rs * g[tid + 512];
  unsigned short* hr = h + (long)row * 768;
  hr[tid] = f2bf(h0); hr[tid + 256] = f2bf(h1); hr[tid + 512] = f2bf(h2);
  float p = h0 * h0 + h1 * h1 + h2 * h2;
  #pragma unroll
  for (int o = 32; o; o >>= 1) p += __shfl_xor(p, o);
  if ((tid & 63) == 0) red[8 + wv] = p;
  __syncthreads();
  if (tid == 0) row2[row] = red[8] + red[9] + red[10] + red[11];
}

// ---------------- yat GEMM: 64x128 tile, 3-buffer distance-2, XCD swizzle ---
constexpr int M_QKV = 0, M_AO = 1, M_PART = 2;

struct GemmArgs {
  const unsigned short* A; const unsigned short* Bt;
  const float* arow2; const float* wcol2; const float* bias; const float* alpha;
  int N; int ks;
  const float* rope;                                    // QKV
  unsigned short* qo; unsigned short* ko; unsigned short* vo;  // QKV
  const float* xf; float* xo;                           // AO: residual in/out (f32)
  unsigned short* partb;                                // PART: bf16 slab base
};

template <int MODE, int NI, int NBM, int NBN, int NZ>
__global__ __launch_bounds__(256, 4) void k_gemm(GemmArgs p) {
  __shared__ __align__(16) unsigned short As[3][2048];   // 64 x 32
  __shared__ __align__(16) unsigned short Bs[3][4096];   // 128 x 32
  const int tid = threadIdx.x, wave = tid >> 6, lane = tid & 63;
  const int quad = lane >> 4, l = lane & 15;
  constexpr int TOTAL = NBM * NBN * NZ;
  const int g = xcd_swizzle(blockIdx.x, TOTAL);
  const int bm = (g % NBM) * 64;
  const int rest = g / NBM;
  const int bn = (rest % NBN) * 128;
  const int z = rest / NBN;
  const int kb = z * (NI * 32);
  const int ks = p.ks;
  const int wm = (wave & 1) * 32, wn = (wave >> 1) * 64;
  const f32x4 fzero = {0.f, 0.f, 0.f, 0.f};
  f32x4 acc[2][4];
  #pragma unroll
  for (int i = 0; i < 2; ++i)
    #pragma unroll
    for (int j = 0; j < 4; ++j) acc[i][j] = fzero;
  const int sw = (l >> 1) & 3;

  // hoisted per-thread staging pointers (advance +32 elements per stage call)
  const int r0 = tid >> 2;
  const int c0 = (tid & 3) ^ ((r0 >> 1) & 3);
  const unsigned short* ap  = p.A  + (long)(bm + r0) * ks + kb + c0 * 8;
  const unsigned short* bp0 = p.Bt + (long)(bn + r0) * ks + kb + c0 * 8;
  const unsigned short* bp1 = bp0 + (long)64 * ks;

  auto stage = [&](int s) {
    async16(ap,  &As[s][tid * 8]);
    async16(bp0, &Bs[s][tid * 8]);
    async16(bp1, &Bs[s][(tid + 256) * 8]);
    ap += 32; bp0 += 32; bp1 += 32;
  };
  auto compute = [&](int s) {
    bf16x8 af[2], bfv[4];
    #pragma unroll
    for (int mi = 0; mi < 2; ++mi)
      af[mi] = *(const bf16x8*)&As[s][(wm + mi * 16 + l) * 32 + ((quad ^ sw) * 8)];
    #pragma unroll
    for (int ni = 0; ni < 4; ++ni)
      bfv[ni] = *(const bf16x8*)&Bs[s][(wn + ni * 16 + l) * 32 + ((quad ^ sw) * 8)];
    #pragma unroll
    for (int mi = 0; mi < 2; ++mi)
      #pragma unroll
      for (int ni = 0; ni < 4; ++ni)
        acc[mi][ni] = __builtin_amdgcn_mfma_f32_16x16x32_bf16(af[mi], bfv[ni], acc[mi][ni], 0, 0, 0);
  };
  auto iter = [&](int s, int i) {
    if (i + 1 >= NI) { asm volatile("s_waitcnt vmcnt(0)" ::: "memory"); }
    else             { asm volatile("s_waitcnt vmcnt(3)" ::: "memory"); }
    __builtin_amdgcn_s_barrier();
    asm volatile("" ::: "memory");
    if (i + 2 < NI) stage(s == 0 ? 2 : s - 1);
    compute(s);
  };

  stage(0);
  stage(1);
  int i = 0;
  while (i < NI) {          // NI % 3 == 0
    iter(0, i); ++i;
    iter(1, i); ++i;
    iter(2, i); ++i;
  }

  if constexpr (MODE == M_PART) {
    unsigned short* slab = p.partb + (long)z * (2048 * 768);
    #pragma unroll
    for (int ni = 0; ni < 4; ++ni) {
      const int j = bn + wn + ni * 16 + l;
      #pragma unroll
      for (int mi = 0; mi < 2; ++mi) {
        const int i0 = bm + wm + mi * 16 + quad * 4;
        #pragma unroll
        for (int rg = 0; rg < 4; ++rg)
          slab[(long)(i0 + rg) * 768 + j] = f2bf(acc[mi][ni][rg]);
      }
    }
  } else {
    const float al = p.alpha[0];
    const float nn = (float)p.N;
    const float ys = powf(sqrtf(nn) / log1pf(nn), al);
    #pragma unroll
    for (int ni = 0; ni < 4; ++ni) {
      const int j = bn + wn + ni * 16 + l;
      const float w2 = p.wcol2[j];
      const float bj = p.bias[j];
      int s3 = 0, hh = 0, dd = 0;
      if constexpr (MODE == M_QKV) { s3 = j / 768; int rem = j - s3 * 768; hh = rem >> 6; dd = rem & 63; }
      #pragma unroll
      for (int mi = 0; mi < 2; ++mi) {
        const int i0 = bm + wm + mi * 16 + quad * 4;
        float vv[4];
        #pragma unroll
        for (int rg = 0; rg < 4; ++rg) {
          const float y = acc[mi][ni][rg];
          const float dist = p.arow2[i0 + rg] + w2 - 2.f * y + 1e-6f;
          vv[rg] = (__fdividef(y * y, dist) + bj) * ys;
        }
        if constexpr (MODE == M_QKV) {
          int b = i0 >> 10, t0 = i0 & 1023;
          if (s3 == 2) {
            us4 pk = {f2bf(vv[0]), f2bf(vv[1]), f2bf(vv[2]), f2bf(vv[3])};
            *(us4*)&p.vo[((long)(b * 12 + hh) * 64 + dd) * 1024 + t0] = pk;    // V^T (B,H,D,T)
          } else {
            unsigned short* dst = (s3 == 0) ? p.qo : p.ko;                     // (B,H,T,D)
            #pragma unroll
            for (int rg = 0; rg < 4; ++rg) {
              float ro = p.rope[(t0 + rg) * 64 + dd];
              dst[((long)(b * 12 + hh) * 1024 + t0 + rg) * 64 + dd] = f2bf(vv[rg] * ro);
            }
          }
        } else {  // M_AO (unused in this config; kept for completeness)
          #pragma unroll
          for (int rg = 0; rg < 4; ++rg) {
            long idx = (long)(i0 + rg) * 768 + j;
            p.xo[idx] = p.xf[idx] + vv[rg];
          }
        }
      }
    }
  }
}

// ---- AO yat GEMM: 64x64 tile, 384 blocks for co-residency overlap ----------
// R8: M_AO at 64x128 gave only 192 blocks on 256 CUs -> zero inter-block
// overlap on 75% of CUs (the overlap that feeds k_mlp's pipes, m114).
// 64x64 tile doubles the grid: all 384 co-resident, >=1.5 blocks/CU.
// Same 3-buffer dist-2 schedule; 2 async16/stage -> steady vmcnt(2).
__global__ __launch_bounds__(256, 4) void k_gemm_ao(GemmArgs p) {
  constexpr int NI = 24;
  __shared__ __align__(16) unsigned short As[3][2048];   // 64 x 32
  __shared__ __align__(16) unsigned short Bs[3][2048];   // 64 x 32
  const int tid = threadIdx.x, wave = tid >> 6, lane = tid & 63;
  const int quad = lane >> 4, l = lane & 15;
  const int g = xcd_swizzle(blockIdx.x, 32 * 12);
  const int bm = (g % 32) * 64;
  const int bn = (g / 32) * 64;
  const int ks = p.ks;
  const int wm = (wave & 1) * 32, wn = (wave >> 1) * 32;
  const f32x4 fzero = {0.f, 0.f, 0.f, 0.f};
  f32x4 acc[2][2];
  #pragma unroll
  for (int i = 0; i < 2; ++i)
    #pragma unroll
    for (int j = 0; j < 2; ++j) acc[i][j] = fzero;
  const int sw = (l >> 1) & 3;

  const int r0 = tid >> 2;
  const int c0 = (tid & 3) ^ ((r0 >> 1) & 3);
  const unsigned short* ap = p.A  + (long)(bm + r0) * ks + c0 * 8;
  const unsigned short* bp = p.Bt + (long)(bn + r0) * ks + c0 * 8;

  auto stage = [&](int s) {
    async16(ap, &As[s][tid * 8]);
    async16(bp, &Bs[s][tid * 8]);
    ap += 32; bp += 32;
  };
  auto compute = [&](int s) {
    bf16x8 af[2], bfv[2];
    #pragma unroll
    for (int mi = 0; mi < 2; ++mi)
      af[mi] = *(const bf16x8*)&As[s][(wm + mi * 16 + l) * 32 + ((quad ^ sw) * 8)];
    #pragma unroll
    for (int ni = 0; ni < 2; ++ni)
      bfv[ni] = *(const bf16x8*)&Bs[s][(wn + ni * 16 + l) * 32 + ((quad ^ sw) * 8)];
    #pragma unroll
    for (int mi = 0; mi < 2; ++mi)
      #pragma unroll
      for (int ni = 0; ni < 2; ++ni)
        acc[mi][ni] = __builtin_amdgcn_mfma_f32_16x16x32_bf16(af[mi], bfv[ni], acc[mi][ni], 0, 0, 0);
  };
  auto iter = [&](int s, int i) {
    if (i + 1 >= NI) { asm volatile("s_waitcnt vmcnt(0)" ::: "memory"); }
    else             { asm volatile("s_waitcnt vmcnt(2)" ::: "memory"); }
    __builtin_amdgcn_s_barrier();
    asm volatile("" ::: "memory");
    if (i + 2 < NI) stage((i + 2) % 3);
    compute(s);
  };

  stage(0);
  stage(1);
  int i = 0;
  while (i < NI) {          // NI % 3 == 0
    iter(0, i); ++i;
    iter(1, i); ++i;
    iter(2, i); ++i;
  }

  const float ys = powf(sqrtf(768.f) / log1pf(768.f), p.alpha[0]);
  #pragma unroll
  for (int ni = 0; ni < 2; ++ni) {
    const int j = bn + wn + ni * 16 + l;
    const float w2 = p.wcol2[j];
    const float bj = p.bias[j];
    #pragma unroll
    for (int mi = 0; mi < 2; ++mi) {
      const int i0 = bm + wm + mi * 16 + quad * 4;
      #pragma unroll
      for (int rg = 0; rg < 4; ++rg) {
        const float y = acc[mi][ni][rg];
        const float dist = p.arow2[i0 + rg] + w2 - 2.f * y + 1e-6f;
        long idx = (long)(i0 + rg) * 768 + j;
        p.xo[idx] = p.xf[idx] + (__fdividef(y * y, dist) + bj) * ys;
      }
    }
  }
}

// ---------------- PROJ reduce (4 bf16 slabs) + yat epilogue + residual ------
struct EpiArgs {
  const unsigned short* slab; const float* arow2; const float* wcol2;
  const float* bias; const float* alpha; const float* xo; float* outf;
};
__global__ __launch_bounds__(256) void k_proj_epi(EpiArgs p) {
  int g = blockIdx.x * 256 + threadIdx.x;   // 393216 = 2048*768/4
  int i = g / 192, jv = (g - i * 192) * 4;
  long base = (long)i * 768 + jv;
  f32x4 y = {0.f, 0.f, 0.f, 0.f};
  #pragma unroll
  for (int z = 0; z < 4; ++z) {
    us4 s4 = *(const us4*)(p.slab + (long)z * 1572864 + base);
    #pragma unroll
    for (int c = 0; c < 4; ++c) y[c] += bf2f(s4[c]);
  }
  const float a2 = p.arow2[i];
  const float ys = powf(sqrtf(768.f) / log1pf(768.f), p.alpha[0]);
  f32x4 xo4 = *(const f32x4*)(p.xo + base);
  f32x4 out;
  #pragma unroll
  for (int c = 0; c < 4; ++c) {
    float yy = y[c];
    float dist = a2 + p.wcol2[jv + c] - 2.f * yy + 1e-6f;
    out[c] = xo4[c] + (__fdividef(yy * yy, dist) + p.bias[jv + c]) * ys;
  }
  *(f32x4*)(p.outf + base) = out;
}

// ---- merged FC+GATE yat GEMM: 128x64 tile, A+B all LDS-staged, 3-buffer ----
// (R4 best-measured version: 43.6 us. Structure-limited; frozen.)
struct MlpArgs {
  const unsigned short* A; const unsigned short* Bf; const unsigned short* Bg;
  const float* arow2; const float* w2f; const float* w2g;
  const float* bf; const float* bg; const float* af_; const float* ag_;
  unsigned short* mlp; float* mrow2;
};

__global__ __launch_bounds__(256, 3) void k_mlp(MlpArgs p) {
  constexpr int NI = 24, K = 768;
  __shared__ __align__(16) unsigned short As[3][4096];    // 128 x 32
  __shared__ __align__(16) unsigned short Bfs[3][2048];   // 64 x 32
  __shared__ __align__(16) unsigned short Bgs[3][2048];   // 64 x 32
  const int tid = threadIdx.x, wave = tid >> 6, lane = tid & 63;
  const int quad = lane >> 4, l = lane & 15;
  const int g = xcd_swizzle(blockIdx.x, 16 * 48);
  const int bm = (g % 16) * 128, bn = (g / 16) * 64;
  const int wm = wave * 32;                // 4 waves x 32 rows; all share 64 cols
  const f32x4 fzero = {0.f, 0.f, 0.f, 0.f};
  f32x4 accf[2][4], accg[2][4];
  #pragma unroll
  for (int i = 0; i < 2; ++i)
    #pragma unroll
    for (int j = 0; j < 4; ++j) { accf[i][j] = fzero; accg[i][j] = fzero; }
  const int sw = (l >> 1) & 3;

  // hoisted per-thread staging pointers (advance +32 elements per stage call)
  const int r0 = tid >> 2;
  const int c0 = (tid & 3) ^ ((r0 >> 1) & 3);
  const unsigned short* ap0 = p.A  + (long)(bm + r0) * K + c0 * 8;
  const unsigned short* ap1 = ap0 + (long)64 * K;
  const unsigned short* bfp = p.Bf + (long)(bn + r0) * K + c0 * 8;
  const unsigned short* bgp = p.Bg + (long)(bn + r0) * K + c0 * 8;

  auto stage = [&](int s) {
    async16(ap0, &As[s][tid * 8]);
    async16(ap1, &As[s][(tid + 256) * 8]);
    async16(bfp, &Bfs[s][tid * 8]);
    async16(bgp, &Bgs[s][tid * 8]);
    ap0 += 32; ap1 += 32; bfp += 32; bgp += 32;
  };
  auto compute = [&](int s) {
    bf16x8 af[2], bff[4], bfg[4];
    #pragma unroll
    for (int mi = 0; mi < 2; ++mi)
      af[mi] = *(const bf16x8*)&As[s][(wm + mi * 16 + l) * 32 + ((quad ^ sw) * 8)];
    #pragma unroll
    for (int ni = 0; ni < 4; ++ni) {
      bff[ni] = *(const bf16x8*)&Bfs[s][(ni * 16 + l) * 32 + ((quad ^ sw) * 8)];
      bfg[ni] = *(const bf16x8*)&Bgs[s][(ni * 16 + l) * 32 + ((quad ^ sw) * 8)];
    }
    __builtin_amdgcn_s_setprio(1);
    #pragma unroll
    for (int ni = 0; ni < 4; ++ni) {
      accf[0][ni] = __builtin_amdgcn_mfma_f32_16x16x32_bf16(af[0], bff[ni], accf[0][ni], 0, 0, 0);
      accg[0][ni] = __builtin_amdgcn_mfma_f32_16x16x32_bf16(af[0], bfg[ni], accg[0][ni], 0, 0, 0);
      accf[1][ni] = __builtin_amdgcn_mfma_f32_16x16x32_bf16(af[1], bff[ni], accf[1][ni], 0, 0, 0);
      accg[1][ni] = __builtin_amdgcn_mfma_f32_16x16x32_bf16(af[1], bfg[ni], accg[1][ni], 0, 0, 0);
    }
    __builtin_amdgcn_s_setprio(0);
  };
  auto iter = [&](int s, int i) {
    if (i + 1 >= NI) { asm volatile("s_waitcnt vmcnt(0)" ::: "memory"); }
    else             { asm volatile("s_waitcnt vmcnt(4)" ::: "memory"); }
    __builtin_amdgcn_s_barrier();
    asm volatile("" ::: "memory");
    if (i + 2 < NI) stage((i + 2) % 3);
    compute(s);
  };

  stage(0);
  stage(1);
  int i = 0;
  while (i < NI) {          // NI % 3 == 0
    iter(0, i); ++i;
    iter(1, i); ++i;
    iter(2, i); ++i;
  }

  const float ysf = powf(sqrtf(3072.f) / log1pf(3072.f), p.af_[0]);
  const float ysg = powf(sqrtf(3072.f) / log1pf(3072.f), p.ag_[0]);
  float w2f[4], w2g[4], bjf[4], bjg[4]; int js[4];
  #pragma unroll
  for (int ni = 0; ni < 4; ++ni) {
    int j = bn + ni * 16 + l;
    js[ni] = j; w2f[ni] = p.w2f[j]; w2g[ni] = p.w2g[j]; bjf[ni] = p.bf[j]; bjg[ni] = p.bg[j];
  }
  #pragma unroll
  for (int mi = 0; mi < 2; ++mi) {
    #pragma unroll
    for (int rg = 0; rg < 4; ++rg) {
      const int ii = bm + wm + mi * 16 + quad * 4 + rg;
      const float a2 = p.arow2[ii];
      float rsum = 0.f;
      #pragma unroll
      for (int ni = 0; ni < 4; ++ni) {
        float yf = accf[mi][ni][rg];
        float gate = (__fdividef(yf * yf, a2 + w2f[ni] - 2.f * yf + 1e-6f) + bjf[ni]) * ysf;
        float yg = accg[mi][ni][rg];
        float u  = (__fdividef(yg * yg, a2 + w2g[ni] - 2.f * yg + 1e-6f) + bjg[ni]) * ysg;
        float out = gelu_t(u) * gate;
        p.mlp[(long)ii * 3072 + js[ni]] = f2bf(out);
        rsum += out * out;
      }
      #pragma unroll
      for (int o = 8; o; o >>= 1) rsum += __shfl_xor(rsum, o);
      if (l == 0) atomicAdd(&p.mrow2[ii], rsum);
    }
  }
}

// ---------------- flash attention: 64-row Q tiles, causal, prefetched -------
// (R4 best-measured version: staged K+V, dist-2, no setprio. Frozen --
//  R6 1-wave and R7 V-direct variants both regressed.)
__global__ __launch_bounds__(256) void k_attn(const unsigned short* __restrict__ qb,
    const unsigned short* __restrict__ kb, const unsigned short* __restrict__ vb,
    unsigned short* __restrict__ ob, float* __restrict__ orow2) {
  __shared__ __align__(16) unsigned short Qs[4096];
  __shared__ __align__(16) unsigned short Ks[3][4096];
  __shared__ __align__(16) unsigned short Vs[3][4096];
  __shared__ __align__(16) unsigned short Ps[4096];
  const int tid = threadIdx.x, wave = tid >> 6, lane = tid & 63;
  const int quad = lane >> 4, l = lane & 15;
  const int g = xcd_swizzle(blockIdx.x, 16 * 24);
  const int bh = g % 24, qt = 15 - (g / 24);   // heavy q-tiles first
  const int b = bh / 12, hh = bh % 12;
  const int q0 = qt * 64;
  const f32x4 fzero = {0.f, 0.f, 0.f, 0.f};

  // hoisted K/V staging pointers (sequential jt; advance per stage_kv call)
  const int rkv = tid >> 3;                       // 0..31
  const int ckv = (tid & 7) ^ (rkv & 7);
  const unsigned short* kp0 = kb + ((long)bh * 1024 + rkv) * 64 + ckv * 8;
  const unsigned short* kp1 = kp0 + (long)32 * 64;
  const unsigned short* vp0 = vb + (long)bh * 65536 + (long)rkv * 1024 + ckv * 8;
  const unsigned short* vp1 = vp0 + (long)32 * 1024;

  auto stage_kv = [&](int s) {
    async16(kp0, &Ks[s][tid * 8]);
    async16(vp0, &Vs[s][tid * 8]);
    async16(kp1, &Ks[s][(tid + 256) * 8]);
    async16(vp1, &Vs[s][(tid + 256) * 8]);
    kp0 += 4096; kp1 += 4096;    // next 64 K-rows
    vp0 += 64;   vp1 += 64;      // next 64 t-columns
  };

  const unsigned short* qg = qb + ((long)bh * 1024 + q0) * 64;
  #pragma unroll
  for (int it = 0; it < 2; ++it) {
    int ci = tid + it * 256;
    int r = ci >> 3;
    int c = (ci & 7) ^ (r & 7);
    async16(qg + (long)r * 64 + c * 8, &Qs[ci * 8]);
  }
  stage_kv(0);
  if (qt >= 1) {
    stage_kv(1);
    asm volatile("s_waitcnt vmcnt(4)" ::: "memory");
  } else {
    asm volatile("s_waitcnt vmcnt(0)" ::: "memory");
  }
  __builtin_amdgcn_s_barrier();
  asm volatile("" ::: "memory");

  bf16x8 aq[2];
  #pragma unroll
  for (int ks = 0; ks < 2; ++ks)
    aq[ks] = *(const bf16x8*)&Qs[(wave * 16 + l) * 64 + (((ks * 4 + quad) ^ (l & 7)) * 8)];

  f32x4 O[4];
  float mi_[4], li[4];
  #pragma unroll
  for (int f = 0; f < 4; ++f) O[f] = fzero;
  #pragma unroll
  for (int r = 0; r < 4; ++r) { mi_[r] = -1e30f; li[r] = 0.f; }

  for (int jt = 0; jt <= qt; ++jt) {
    const int s = jt % 3;
    if (jt > 0) {
      if (jt + 1 <= qt) { asm volatile("s_waitcnt vmcnt(4)" ::: "memory"); }
      else              { asm volatile("s_waitcnt vmcnt(0)" ::: "memory"); }
      __builtin_amdgcn_s_barrier();
      asm volatile("" ::: "memory");
    }
    if (jt + 2 <= qt) stage_kv((jt + 2) % 3);

    f32x4 S[4];
    #pragma unroll
    for (int f = 0; f < 4; ++f) S[f] = fzero;
    #pragma unroll
    for (int ks = 0; ks < 2; ++ks) {
      #pragma unroll
      for (int f = 0; f < 4; ++f) {
        bf16x8 bk = *(const bf16x8*)&Ks[s][(f * 16 + l) * 64 + (((ks * 4 + quad) ^ (l & 7)) * 8)];
        S[f] = __builtin_amdgcn_mfma_f32_16x16x32_bf16(aq[ks], bk, S[f], 0, 0, 0);
      }
    }
    const bool diag = (jt == qt);
    #pragma unroll
    for (int f = 0; f < 4; ++f)
      #pragma unroll
      for (int r = 0; r < 4; ++r) {
        float v = S[f][r] * 0.125f;
        if (diag && (f * 16 + l > wave * 16 + quad * 4 + r)) v = -1e30f;
        S[f][r] = v;
      }
    #pragma unroll
    for (int r = 0; r < 4; ++r) {
      float mx = fmaxf(fmaxf(S[0][r], S[1][r]), fmaxf(S[2][r], S[3][r]));
      #pragma unroll
      for (int o = 8; o; o >>= 1) mx = fmaxf(mx, __shfl_xor(mx, o));
      float mnew = fmaxf(mi_[r], mx);
      float alr = __expf(mi_[r] - mnew);
      float sum = 0.f;
      #pragma unroll
      for (int f = 0; f < 4; ++f) {
        float e = __expf(S[f][r] - mnew);
        S[f][r] = e;
        sum += e;
      }
      #pragma unroll
      for (int o = 8; o; o >>= 1) sum += __shfl_xor(sum, o);
      li[r] = li[r] * alr + sum;
      #pragma unroll
      for (int f = 0; f < 4; ++f) O[f][r] *= alr;
      mi_[r] = mnew;
    }
    #pragma unroll
    for (int f = 0; f < 4; ++f)
      #pragma unroll
      for (int r = 0; r < 4; ++r) {
        int i = quad * 4 + r;
        int j = f * 16 + l;
        int pch = (j >> 3) ^ (i & 7);
        Ps[wave * 1024 + i * 64 + pch * 8 + (j & 7)] = f2bf(S[f][r]);
      }
    #pragma unroll
    for (int ks = 0; ks < 2; ++ks) {
      bf16x8 ap = *(const bf16x8*)&Ps[wave * 1024 + l * 64 + (((ks * 4 + quad) ^ (l & 7)) * 8)];
      #pragma unroll
      for (int f = 0; f < 4; ++f) {
        bf16x8 bv = *(const bf16x8*)&Vs[s][(f * 16 + l) * 64 + (((ks * 4 + quad) ^ (l & 7)) * 8)];
        O[f] = __builtin_amdgcn_mfma_f32_16x16x32_bf16(ap, bv, O[f], 0, 0, 0);
      }
    }
  }
  float inv[4];
  #pragma unroll
  for (int r = 0; r < 4; ++r) inv[r] = __fdividef(1.f, li[r]);
  #pragma unroll
  for (int f = 0; f < 4; ++f)
    #pragma unroll
    for (int r = 0; r < 4; ++r) {
      int t = q0 + wave * 16 + quad * 4 + r;
      int dd = f * 16 + l;
      ob[((long)(b * 1024 + t) * 12 + hh) * 64 + dd] = f2bf(O[f][r] * inv[r]);  // (B,T,H,D)
    }
  #pragma unroll
  for (int r = 0; r < 4; ++r) {
    float rsum = 0.f;
    #pragma unroll
    for (int f = 0; f < 4; ++f) { float v = O[f][r] * inv[r]; rsum += v * v; }
    #pragma unroll
    for (int o = 8; o; o >>= 1) rsum += __shfl_xor(rsum, o);
    if (l == 0) {
      int t = q0 + wave * 16 + quad * 4 + r;
      atomicAdd(&orow2[b * 1024 + t], rsum);
    }
  }
}

// ---------------- host ------------------------------------------------------
extern "C" void kernel_launch(void* const* d_in, const int* in_sizes, int n_in,
                              void* d_out, int out_size, void* d_ws, size_t ws_size,
                              hipStream_t stream) {
  (void)in_sizes; (void)n_in; (void)out_size;
  char* w = (char*)d_ws;
  size_t off = 0;
  auto alloc = [&](size_t bytes) -> void* {
    void* p = w + off;
    off = (off + bytes + 255) & ~(size_t)255;
    return p;
  };
  float* rope            = (float*)alloc(65536 * 4);
  unsigned short* wtqkv  = (unsigned short*)alloc((size_t)2304 * 768 * 2);
  unsigned short* wtao   = (unsigned short*)alloc((size_t)768 * 768 * 2);
  unsigned short* wtfc   = (unsigned short*)alloc((size_t)3072 * 768 * 2);
  unsigned short* wtgate = (unsigned short*)alloc((size_t)3072 * 768 * 2);
  unsigned short* wtproj = (unsigned short*)alloc((size_t)768 * 3072 * 2);
  float* zeroed          = (float*)alloc(14080 * 4);   // wcol2(9984) + orow2(2048) + mrow2(2048)
  unsigned short* h1     = (unsigned short*)alloc((size_t)2048 * 768 * 2);
  float* hrow1           = (float*)alloc(2048 * 4);
  unsigned short* qbuf   = (unsigned short*)alloc((size_t)2048 * 768 * 2);
  unsigned short* kbuf   = (unsigned short*)alloc((size_t)2048 * 768 * 2);
  unsigned short* vbuf   = (unsigned short*)alloc((size_t)2048 * 768 * 2);
  unsigned short* obuf   = (unsigned short*)alloc((size_t)2048 * 768 * 2);
  float* xo              = (float*)alloc((size_t)2048 * 768 * 4);
  unsigned short* h2     = (unsigned short*)alloc((size_t)2048 * 768 * 2);
  float* hrow2           = (float*)alloc(2048 * 4);
  unsigned short* mlp    = (unsigned short*)alloc((size_t)2048 * 3072 * 2);
  unsigned short* slabs  = (unsigned short*)alloc((size_t)4 * 2048 * 768 * 2);  // bf16 split-K partials
  if (off > ws_size) return;

  float* wcol2  = zeroed;
  float* orow2  = zeroed + 9984;
  float* mrow2  = zeroed + 9984 + 2048;
  float* c_qkv  = wcol2 + 0;
  float* c_ao   = wcol2 + 2304;
  float* c_fc   = wcol2 + 3072;
  float* c_gate = wcol2 + 6144;
  float* c_proj = wcol2 + 9216;

  const float* xin = (const float*)d_in[0];

  hipMemsetAsync(zeroed, 0, 14080 * 4, stream);

  PrepArgs pa;
  pa.rope = rope;
  pa.W[0] = (const float*)d_in[3];  pa.Wt[0] = wtqkv;  pa.cn[0] = c_qkv;  pa.N[0] = 2304;
  pa.W[1] = (const float*)d_in[6];  pa.Wt[1] = wtao;   pa.cn[1] = c_ao;   pa.N[1] = 768;
  pa.W[2] = (const float*)d_in[10]; pa.Wt[2] = wtfc;   pa.cn[2] = c_fc;   pa.N[2] = 3072;
  pa.W[3] = (const float*)d_in[13]; pa.Wt[3] = wtgate; pa.cn[3] = c_gate; pa.N[3] = 3072;
  pa.W[4] = (const float*)d_in[16]; pa.Wt[4] = wtproj; pa.cn[4] = c_proj; pa.N[4] = 768;
  pa.off[0] = 0; pa.off[1] = 1728; pa.off[2] = 2304; pa.off[3] = 4608;
  pa.off[4] = 6912; pa.off[5] = 9216;
  pa.x = xin; pa.g1s = (const float*)d_in[2]; pa.h1 = h1; pa.hrow1 = hrow1;
  k_prep<<<11520, 256, 0, stream>>>(pa);

  GemmArgs gq = {};
  gq.A = h1; gq.Bt = wtqkv; gq.arow2 = hrow1; gq.wcol2 = c_qkv;
  gq.bias = (const float*)d_in[4]; gq.alpha = (const float*)d_in[5];
  gq.N = 2304; gq.ks = 768;
  gq.rope = rope; gq.qo = qbuf; gq.ko = kbuf; gq.vo = vbuf;
  k_gemm<M_QKV, 24, 32, 18, 1><<<576, 256, 0, stream>>>(gq);

  k_attn<<<384, 256, 0, stream>>>(qbuf, kbuf, vbuf, obuf, orow2);

  GemmArgs ga = {};
  ga.A = obuf; ga.Bt = wtao; ga.arow2 = orow2; ga.wcol2 = c_ao;
  ga.bias = (const float*)d_in[7]; ga.alpha = (const float*)d_in[8];
  ga.N = 768; ga.ks = 768;
  ga.xf = xin; ga.xo = xo;
  k_gemm_ao<<<384, 256, 0, stream>>>(ga);

  k_ln<<<2048, 256, 0, stream>>>(xo, (const float*)d_in[9], h2, hrow2);

  MlpArgs gm = {};
  gm.A = h2; gm.Bf = wtfc; gm.Bg = wtgate; gm.arow2 = hrow2;
  gm.w2f = c_fc; gm.w2g = c_gate;
  gm.bf = (const float*)d_in[11]; gm.bg = (const float*)d_in[14];
  gm.af_ = (const float*)d_in[12]; gm.ag_ = (const float*)d_in[15];
  gm.mlp = mlp; gm.mrow2 = mrow2;
  k_mlp<<<768, 256, 0, stream>>>(gm);

  GemmArgs gp = {};
  gp.A = mlp; gp.Bt = wtproj;
  gp.N = 768; gp.ks = 3072;
  gp.partb = slabs;
  k_gemm<M_PART, 24, 32, 6, 4><<<768, 256, 0, stream>>>(gp);

  EpiArgs ge = {};
  ge.slab = slabs; ge.arow2 = mrow2; ge.wcol2 = c_proj;
  ge.bias = (const float*)d_in[17]; ge.alpha = (const float*)d_in[18];
  ge.xo = xo; ge.outf = (float*)d_out;
  k_proj_epi<<<1536, 256, 0, stream>>>(ge);
}

// Round 10
// 261.609 us; speedup vs baseline: 1.0723x; 1.0067x over previous
//
#include <hip/hip_runtime.h>
#include <cstdint>

#define DEVFN static __device__ __forceinline__

typedef __bf16 bf16x8 __attribute__((ext_vector_type(8)));
typedef float f32x4 __attribute__((ext_vector_type(4)));
typedef unsigned short us4 __attribute__((ext_vector_type(4)));

DEVFN unsigned short f2bf(float f) {
  unsigned u = __float_as_uint(f);
  u += 0x7fffu + ((u >> 16) & 1u);           // round-to-nearest-even
  return (unsigned short)(u >> 16);
}
DEVFN float bf2f(unsigned short h) { return __uint_as_float(((unsigned)h) << 16); }
DEVFN void async16(const void* g, void* l) {
  __builtin_amdgcn_global_load_lds((__attribute__((address_space(1))) const void*)g,
                                   (__attribute__((address_space(3))) void*)l, 16, 0, 0);
}
// gelu(tanh approx) == u * sigmoid(2z), z = 0.79788456*(u+0.044715u^3)  (exact identity)
DEVFN float gelu_t(float u) {
  float z = 0.7978845608028654f * (u + 0.044715f * u * u * u);
  float zc = fminf(fmaxf(z, -15.f), 15.f);
  float e = __expf(2.f * zc);
  return u * __fdividef(e, e + 1.f);
}
// XCD swizzle: lin%8 = XCD class; give each XCD a contiguous slice of g-space
DEVFN int xcd_swizzle(int lin, int total) {
  return (lin & 7) * (total >> 3) + (lin >> 3);
}

// ---------------- merged prep: rope + 5 transposes (64x64) + LN1 ------------
// R10: transpose tiles 32x32 -> 64x64. Full 256B/wave coalesced reads,
// 128B contiguous bf16 writes, 1 barrier per 4096 elems (was 1/1024),
// 2304 transpose blocks (was 9216). Index algebra: Wt[n][k] = W[k][n],
// n = tn*64+rr, k = tk*64+tx; tile[64][65] padding -> conflict-free.
struct PrepArgs {
  float* rope;
  const float* W[5]; unsigned short* Wt[5]; float* cn[5];
  int N[5]; int off[6];
  const float* x; const float* g1s; unsigned short* h1; float* hrow1;
};
__global__ __launch_bounds__(256) void k_prep(PrepArgs a) {
  __shared__ float tile[64][65];
  __shared__ float part[4][64];
  __shared__ float red[12];
  const int bid = blockIdx.x, tid = threadIdx.x;
  if (bid < 256) {                       // rope table
    int g = bid * 256 + tid;
    int t = g >> 6, dd = g & 63, i = dd & 31;
    float fr = __expf(-0.2878231366242558f * (float)i);   // ln(1e4)/32
    float ang = (float)t * fr;
    a.rope[g] = (dd < 32) ? cosf(ang) : sinf(ang);
  } else if (bid < 2560) {               // weight transpose + col sq-norms
    int lin = bid - 256;
    int e = 0;
    while (lin >= a.off[e + 1]) ++e;
    int local = lin - a.off[e];
    const int N = a.N[e];
    int nbx = N >> 6;
    int tn = local % nbx, tk = local / nbx;
    const float* W = a.W[e];
    unsigned short* Wt = a.Wt[e];
    float* cn = a.cn[e];
    const int K = (e == 4) ? 3072 : 768;
    int tx = tid & 63, ty = tid >> 6;    // ty 0..3
    float acc = 0.f;
    #pragma unroll
    for (int j = 0; j < 16; ++j) {
      int r = ty + j * 4;                // 0..63
      float v = W[(long)(tk * 64 + r) * N + tn * 64 + tx];
      tile[r][tx] = v;
      acc += v * v;
    }
    part[ty][tx] = acc;
    __syncthreads();
    #pragma unroll
    for (int j = 0; j < 16; ++j) {
      int rr = ty + j * 4;
      Wt[(long)(tn * 64 + rr) * K + tk * 64 + tx] = f2bf(tile[tx][rr]);
    }
    if (ty == 0) {
      float s = part[0][tx] + part[1][tx] + part[2][tx] + part[3][tx];
      atomicAdd(&cn[tn * 64 + tx], s);
    }
  } else {                               // LN1
    int row = bid - 2560;
    const float* xr = a.x + (long)row * 768;
    float v0 = xr[tid], v1 = xr[tid + 256], v2 = xr[tid + 512];
    float s = v0 + v1 + v2;
    float ss = v0 * v0 + v1 * v1 + v2 * v2;
    #pragma unroll
    for (int o = 32; o; o >>= 1) { s += __shfl_xor(s, o); ss += __shfl_xor(ss, o); }
    int wv = tid >> 6;
    if ((tid & 63) == 0) { red[wv] = s; red[wv + 4] = ss; }
    __syncthreads();
    s = red[0] + red[1] + red[2] + red[3];
    ss = red[4] + red[5] + red[6] + red[7];
    float mu = s * (1.f / 768.f);
    float var = ss * (1.f / 768.f) - mu * mu;
    float rs = rsqrtf(var + 1e-6f);
    float h0 = (v0 - mu) * rs * a.g1s[tid];
    float h1 = (v1 - mu) * rs * a.g1s[tid + 256];
    float h2 = (v2 - mu) * rs * a.g1s[tid + 512];
    unsigned short* hr = a.h1 + (long)row * 768;
    hr[tid] = f2bf(h0); hr[tid + 256] = f2bf(h1); hr[tid + 512] = f2bf(h2);
    float p = h0 * h0 + h1 * h1 + h2 * h2;
    #pragma unroll
    for (int o = 32; o; o >>= 1) p += __shfl_xor(p, o);
    if ((tid & 63) == 0) red[8 + wv] = p;
    __syncthreads();
    if (tid == 0) a.hrow1[row] = red[8] + red[9] + red[10] + red[11];
  }
}

// ---------------- layernorm (f32 in) -> bf16 h + row sum(h^2) ---------------
__global__ __launch_bounds__(256) void k_ln(const float* __restrict__ x,
    const float* __restrict__ g, unsigned short* __restrict__ h, float* __restrict__ row2) {
  int row = blockIdx.x, tid = threadIdx.x;
  const float* xr = x + (long)row * 768;
  float v0 = xr[tid], v1 = xr[tid + 256], v2 = xr[tid + 512];
  float s = v0 + v1 + v2;
  float ss = v0 * v0 + v1 * v1 + v2 * v2;
  #pragma unroll
  for (int o = 32; o; o >>= 1) { s += __shfl_xor(s, o); ss += __shfl_xor(ss, o); }
  __shared__ float red[12];
  int wv = tid >> 6;
  if ((tid & 63) == 0) { red[wv] = s; red[wv + 4] = ss; }
  __syncthreads();
  s = red[0] + red[1] + red[2] + red[3];
  ss = red[4] + red[5] + red[6] + red[7];
  float mu = s * (1.f / 768.f);
  float var = ss * (1.f / 768.f) - mu * mu;
  float rs = rsqrtf(var + 1e-6f);
  float h0 = (v0 - mu) * rs * g[tid];
  float h1 = (v1 - mu) * rs * g[tid + 256];
  float h2 = (v2 - mu) * rs * g[tid + 512];
  unsigned short* hr = h + (long)row * 768;
  hr[tid] = f2bf(h0); hr[tid + 256] = f2bf(h1); hr[tid + 512] = f2bf(h2);
  float p = h0 * h0 + h1 * h1 + h2 * h2;
  #pragma unroll
  for (int o = 32; o; o >>= 1) p += __shfl_xor(p, o);
  if ((tid & 63) == 0) red[8 + wv] = p;
  __syncthreads();
  if (tid == 0) row2[row] = red[8] + red[9] + red[10] + red[11];
}

// ---------------- yat GEMM: 64x128 tile, 3-buffer distance-2, XCD swizzle ---
constexpr int M_QKV = 0, M_AO = 1, M_PART = 2;

struct GemmArgs {
  const unsigned short* A; const unsigned short* Bt;
  const float* arow2; const float* wcol2; const float* bias; const float* alpha;
  int N; int ks;
  const float* rope;                                    // QKV
  unsigned short* qo; unsigned short* ko; unsigned short* vo;  // QKV
  const float* xf; float* xo;                           // AO: residual in/out (f32)
  unsigned short* partb;                                // PART: bf16 slab base
};

template <int MODE, int NI, int NBM, int NBN, int NZ>
__global__ __launch_bounds__(256, 4) void k_gemm(GemmArgs p) {
  __shared__ __align__(16) unsigned short As[3][2048];   // 64 x 32
  __shared__ __align__(16) unsigned short Bs[3][4096];   // 128 x 32
  const int tid = threadIdx.x, wave = tid >> 6, lane = tid & 63;
  const int quad = lane >> 4, l = lane & 15;
  constexpr int TOTAL = NBM * NBN * NZ;
  const int g = xcd_swizzle(blockIdx.x, TOTAL);
  const int bm = (g % NBM) * 64;
  const int rest = g / NBM;
  const int bn = (rest % NBN) * 128;
  const int z = rest / NBN;
  const int kb = z * (NI * 32);
  const int ks = p.ks;
  const int wm = (wave & 1) * 32, wn = (wave >> 1) * 64;
  const f32x4 fzero = {0.f, 0.f, 0.f, 0.f};
  f32x4 acc[2][4];
  #pragma unroll
  for (int i = 0; i < 2; ++i)
    #pragma unroll
    for (int j = 0; j < 4; ++j) acc[i][j] = fzero;
  const int sw = (l >> 1) & 3;

  // hoisted per-thread staging pointers (advance +32 elements per stage call)
  const int r0 = tid >> 2;
  const int c0 = (tid & 3) ^ ((r0 >> 1) & 3);
  const unsigned short* ap  = p.A  + (long)(bm + r0) * ks + kb + c0 * 8;
  const unsigned short* bp0 = p.Bt + (long)(bn + r0) * ks + kb + c0 * 8;
  const unsigned short* bp1 = bp0 + (long)64 * ks;

  auto stage = [&](int s) {
    async16(ap,  &As[s][tid * 8]);
    async16(bp0, &Bs[s][tid * 8]);
    async16(bp1, &Bs[s][(tid + 256) * 8]);
    ap += 32; bp0 += 32; bp1 += 32;
  };
  auto compute = [&](int s) {
    bf16x8 af[2], bfv[4];
    #pragma unroll
    for (int mi = 0; mi < 2; ++mi)
      af[mi] = *(const bf16x8*)&As[s][(wm + mi * 16 + l) * 32 + ((quad ^ sw) * 8)];
    #pragma unroll
    for (int ni = 0; ni < 4; ++ni)
      bfv[ni] = *(const bf16x8*)&Bs[s][(wn + ni * 16 + l) * 32 + ((quad ^ sw) * 8)];
    #pragma unroll
    for (int mi = 0; mi < 2; ++mi)
      #pragma unroll
      for (int ni = 0; ni < 4; ++ni)
        acc[mi][ni] = __builtin_amdgcn_mfma_f32_16x16x32_bf16(af[mi], bfv[ni], acc[mi][ni], 0, 0, 0);
  };
  auto iter = [&](int s, int i) {
    if (i + 1 >= NI) { asm volatile("s_waitcnt vmcnt(0)" ::: "memory"); }
    else             { asm volatile("s_waitcnt vmcnt(3)" ::: "memory"); }
    __builtin_amdgcn_s_barrier();
    asm volatile("" ::: "memory");
    if (i + 2 < NI) stage(s == 0 ? 2 : s - 1);
    compute(s);
  };

  stage(0);
  stage(1);
  int i = 0;
  while (i < NI) {          // NI % 3 == 0
    iter(0, i); ++i;
    iter(1, i); ++i;
    iter(2, i); ++i;
  }

  if constexpr (MODE == M_PART) {
    unsigned short* slab = p.partb + (long)z * (2048 * 768);
    #pragma unroll
    for (int ni = 0; ni < 4; ++ni) {
      const int j = bn + wn + ni * 16 + l;
      #pragma unroll
      for (int mi = 0; mi < 2; ++mi) {
        const int i0 = bm + wm + mi * 16 + quad * 4;
        #pragma unroll
        for (int rg = 0; rg < 4; ++rg)
          slab[(long)(i0 + rg) * 768 + j] = f2bf(acc[mi][ni][rg]);
      }
    }
  } else {
    const float al = p.alpha[0];
    const float nn = (float)p.N;
    const float ys = powf(sqrtf(nn) / log1pf(nn), al);
    #pragma unroll
    for (int ni = 0; ni < 4; ++ni) {
      const int j = bn + wn + ni * 16 + l;
      const float w2 = p.wcol2[j];
      const float bj = p.bias[j];
      int s3 = 0, hh = 0, dd = 0;
      if constexpr (MODE == M_QKV) { s3 = j / 768; int rem = j - s3 * 768; hh = rem >> 6; dd = rem & 63; }
      #pragma unroll
      for (int mi = 0; mi < 2; ++mi) {
        const int i0 = bm + wm + mi * 16 + quad * 4;
        float vv[4];
        #pragma unroll
        for (int rg = 0; rg < 4; ++rg) {
          const float y = acc[mi][ni][rg];
          const float dist = p.arow2[i0 + rg] + w2 - 2.f * y + 1e-6f;
          vv[rg] = (__fdividef(y * y, dist) + bj) * ys;
        }
        if constexpr (MODE == M_QKV) {
          int b = i0 >> 10, t0 = i0 & 1023;
          if (s3 == 2) {
            us4 pk = {f2bf(vv[0]), f2bf(vv[1]), f2bf(vv[2]), f2bf(vv[3])};
            *(us4*)&p.vo[((long)(b * 12 + hh) * 64 + dd) * 1024 + t0] = pk;    // V^T (B,H,D,T)
          } else {
            unsigned short* dst = (s3 == 0) ? p.qo : p.ko;                     // (B,H,T,D)
            #pragma unroll
            for (int rg = 0; rg < 4; ++rg) {
              float ro = p.rope[(t0 + rg) * 64 + dd];
              dst[((long)(b * 12 + hh) * 1024 + t0 + rg) * 64 + dd] = f2bf(vv[rg] * ro);
            }
          }
        } else {  // M_AO (unused in this config; kept for completeness)
          #pragma unroll
          for (int rg = 0; rg < 4; ++rg) {
            long idx = (long)(i0 + rg) * 768 + j;
            p.xo[idx] = p.xf[idx] + vv[rg];
          }
        }
      }
    }
  }
}

// ---- AO yat GEMM: 64x64 tile, 384 blocks for co-residency overlap ----------
// (R8/R9: all 384 blocks co-resident, >=1.5 blocks/CU; measured win.)
__global__ __launch_bounds__(256, 4) void k_gemm_ao(GemmArgs p) {
  constexpr int NI = 24;
  __shared__ __align__(16) unsigned short As[3][2048];   // 64 x 32
  __shared__ __align__(16) unsigned short Bs[3][2048];   // 64 x 32
  const int tid = threadIdx.x, wave = tid >> 6, lane = tid & 63;
  const int quad = lane >> 4, l = lane & 15;
  const int g = xcd_swizzle(blockIdx.x, 32 * 12);
  const int bm = (g % 32) * 64;
  const int bn = (g / 32) * 64;
  const int ks = p.ks;
  const int wm = (wave & 1) * 32, wn = (wave >> 1) * 32;
  const f32x4 fzero = {0.f, 0.f, 0.f, 0.f};
  f32x4 acc[2][2];
  #pragma unroll
  for (int i = 0; i < 2; ++i)
    #pragma unroll
    for (int j = 0; j < 2; ++j) acc[i][j] = fzero;
  const int sw = (l >> 1) & 3;

  const int r0 = tid >> 2;
  const int c0 = (tid & 3) ^ ((r0 >> 1) & 3);
  const unsigned short* ap = p.A  + (long)(bm + r0) * ks + c0 * 8;
  const unsigned short* bp = p.Bt + (long)(bn + r0) * ks + c0 * 8;

  auto stage = [&](int s) {
    async16(ap, &As[s][tid * 8]);
    async16(bp, &Bs[s][tid * 8]);
    ap += 32; bp += 32;
  };
  auto compute = [&](int s) {
    bf16x8 af[2], bfv[2];
    #pragma unroll
    for (int mi = 0; mi < 2; ++mi)
      af[mi] = *(const bf16x8*)&As[s][(wm + mi * 16 + l) * 32 + ((quad ^ sw) * 8)];
    #pragma unroll
    for (int ni = 0; ni < 2; ++ni)
      bfv[ni] = *(const bf16x8*)&Bs[s][(wn + ni * 16 + l) * 32 + ((quad ^ sw) * 8)];
    #pragma unroll
    for (int mi = 0; mi < 2; ++mi)
      #pragma unroll
      for (int ni = 0; ni < 2; ++ni)
        acc[mi][ni] = __builtin_amdgcn_mfma_f32_16x16x32_bf16(af[mi], bfv[ni], acc[mi][ni], 0, 0, 0);
  };
  auto iter = [&](int s, int i) {
    if (i + 1 >= NI) { asm volatile("s_waitcnt vmcnt(0)" ::: "memory"); }
    else             { asm volatile("s_waitcnt vmcnt(2)" ::: "memory"); }
    __builtin_amdgcn_s_barrier();
    asm volatile("" ::: "memory");
    if (i + 2 < NI) stage((i + 2) % 3);
    compute(s);
  };

  stage(0);
  stage(1);
  int i = 0;
  while (i < NI) {          // NI % 3 == 0
    iter(0, i); ++i;
    iter(1, i); ++i;
    iter(2, i); ++i;
  }

  const float ys = powf(sqrtf(768.f) / log1pf(768.f), p.alpha[0]);
  #pragma unroll
  for (int ni = 0; ni < 2; ++ni) {
    const int j = bn + wn + ni * 16 + l;
    const float w2 = p.wcol2[j];
    const float bj = p.bias[j];
    #pragma unroll
    for (int mi = 0; mi < 2; ++mi) {
      const int i0 = bm + wm + mi * 16 + quad * 4;
      #pragma unroll
      for (int rg = 0; rg < 4; ++rg) {
        const float y = acc[mi][ni][rg];
        const float dist = p.arow2[i0 + rg] + w2 - 2.f * y + 1e-6f;
        long idx = (long)(i0 + rg) * 768 + j;
        p.xo[idx] = p.xf[idx] + (__fdividef(y * y, dist) + bj) * ys;
      }
    }
  }
}

// ---------------- PROJ reduce (4 bf16 slabs) + yat epilogue + residual ------
struct EpiArgs {
  const unsigned short* slab; const float* arow2; const float* wcol2;
  const float* bias; const float* alpha; const float* xo; float* outf;
};
__global__ __launch_bounds__(256) void k_proj_epi(EpiArgs p) {
  int g = blockIdx.x * 256 + threadIdx.x;   // 393216 = 2048*768/4
  int i = g / 192, jv = (g - i * 192) * 4;
  long base = (long)i * 768 + jv;
  f32x4 y = {0.f, 0.f, 0.f, 0.f};
  #pragma unroll
  for (int z = 0; z < 4; ++z) {
    us4 s4 = *(const us4*)(p.slab + (long)z * 1572864 + base);
    #pragma unroll
    for (int c = 0; c < 4; ++c) y[c] += bf2f(s4[c]);
  }
  const float a2 = p.arow2[i];
  const float ys = powf(sqrtf(768.f) / log1pf(768.f), p.alpha[0]);
  f32x4 xo4 = *(const f32x4*)(p.xo + base);
  f32x4 out;
  #pragma unroll
  for (int c = 0; c < 4; ++c) {
    float yy = y[c];
    float dist = a2 + p.wcol2[jv + c] - 2.f * yy + 1e-6f;
    out[c] = xo4[c] + (__fdividef(yy * yy, dist) + p.bias[jv + c]) * ys;
  }
  *(f32x4*)(p.outf + base) = out;
}

// ---- merged FC+GATE yat GEMM: 128x64 tile, A+B all LDS-staged, 3-buffer ----
// (R4 best-measured version: 43.6 us. Structure-limited; frozen.)
struct MlpArgs {
  const unsigned short* A; const unsigned short* Bf; const unsigned short* Bg;
  const float* arow2; const float* w2f; const float* w2g;
  const float* bf; const float* bg; const float* af_; const float* ag_;
  unsigned short* mlp; float* mrow2;
};

__global__ __launch_bounds__(256, 3) void k_mlp(MlpArgs p) {
  constexpr int NI = 24, K = 768;
  __shared__ __align__(16) unsigned short As[3][4096];    // 128 x 32
  __shared__ __align__(16) unsigned short Bfs[3][2048];   // 64 x 32
  __shared__ __align__(16) unsigned short Bgs[3][2048];   // 64 x 32
  const int tid = threadIdx.x, wave = tid >> 6, lane = tid & 63;
  const int quad = lane >> 4, l = lane & 15;
  const int g = xcd_swizzle(blockIdx.x, 16 * 48);
  const int bm = (g % 16) * 128, bn = (g / 16) * 64;
  const int wm = wave * 32;                // 4 waves x 32 rows; all share 64 cols
  const f32x4 fzero = {0.f, 0.f, 0.f, 0.f};
  f32x4 accf[2][4], accg[2][4];
  #pragma unroll
  for (int i = 0; i < 2; ++i)
    #pragma unroll
    for (int j = 0; j < 4; ++j) { accf[i][j] = fzero; accg[i][j] = fzero; }
  const int sw = (l >> 1) & 3;

  // hoisted per-thread staging pointers (advance +32 elements per stage call)
  const int r0 = tid >> 2;
  const int c0 = (tid & 3) ^ ((r0 >> 1) & 3);
  const unsigned short* ap0 = p.A  + (long)(bm + r0) * K + c0 * 8;
  const unsigned short* ap1 = ap0 + (long)64 * K;
  const unsigned short* bfp = p.Bf + (long)(bn + r0) * K + c0 * 8;
  const unsigned short* bgp = p.Bg + (long)(bn + r0) * K + c0 * 8;

  auto stage = [&](int s) {
    async16(ap0, &As[s][tid * 8]);
    async16(ap1, &As[s][(tid + 256) * 8]);
    async16(bfp, &Bfs[s][tid * 8]);
    async16(bgp, &Bgs[s][tid * 8]);
    ap0 += 32; ap1 += 32; bfp += 32; bgp += 32;
  };
  auto compute = [&](int s) {
    bf16x8 af[2], bff[4], bfg[4];
    #pragma unroll
    for (int mi = 0; mi < 2; ++mi)
      af[mi] = *(const bf16x8*)&As[s][(wm + mi * 16 + l) * 32 + ((quad ^ sw) * 8)];
    #pragma unroll
    for (int ni = 0; ni < 4; ++ni) {
      bff[ni] = *(const bf16x8*)&Bfs[s][(ni * 16 + l) * 32 + ((quad ^ sw) * 8)];
      bfg[ni] = *(const bf16x8*)&Bgs[s][(ni * 16 + l) * 32 + ((quad ^ sw) * 8)];
    }
    __builtin_amdgcn_s_setprio(1);
    #pragma unroll
    for (int ni = 0; ni < 4; ++ni) {
      accf[0][ni] = __builtin_amdgcn_mfma_f32_16x16x32_bf16(af[0], bff[ni], accf[0][ni], 0, 0, 0);
      accg[0][ni] = __builtin_amdgcn_mfma_f32_16x16x32_bf16(af[0], bfg[ni], accg[0][ni], 0, 0, 0);
      accf[1][ni] = __builtin_amdgcn_mfma_f32_16x16x32_bf16(af[1], bff[ni], accf[1][ni], 0, 0, 0);
      accg[1][ni] = __builtin_amdgcn_mfma_f32_16x16x32_bf16(af[1], bfg[ni], accg[1][ni], 0, 0, 0);
    }
    __builtin_amdgcn_s_setprio(0);
  };
  auto iter = [&](int s, int i) {
    if (i + 1 >= NI) { asm volatile("s_waitcnt vmcnt(0)" ::: "memory"); }
    else             { asm volatile("s_waitcnt vmcnt(4)" ::: "memory"); }
    __builtin_amdgcn_s_barrier();
    asm volatile("" ::: "memory");
    if (i + 2 < NI) stage((i + 2) % 3);
    compute(s);
  };

  stage(0);
  stage(1);
  int i = 0;
  while (i < NI) {          // NI % 3 == 0
    iter(0, i); ++i;
    iter(1, i); ++i;
    iter(2, i); ++i;
  }

  const float ysf = powf(sqrtf(3072.f) / log1pf(3072.f), p.af_[0]);
  const float ysg = powf(sqrtf(3072.f) / log1pf(3072.f), p.ag_[0]);
  float w2f[4], w2g[4], bjf[4], bjg[4]; int js[4];
  #pragma unroll
  for (int ni = 0; ni < 4; ++ni) {
    int j = bn + ni * 16 + l;
    js[ni] = j; w2f[ni] = p.w2f[j]; w2g[ni] = p.w2g[j]; bjf[ni] = p.bf[j]; bjg[ni] = p.bg[j];
  }
  #pragma unroll
  for (int mi = 0; mi < 2; ++mi) {
    #pragma unroll
    for (int rg = 0; rg < 4; ++rg) {
      const int ii = bm + wm + mi * 16 + quad * 4 + rg;
      const float a2 = p.arow2[ii];
      float rsum = 0.f;
      #pragma unroll
      for (int ni = 0; ni < 4; ++ni) {
        float yf = accf[mi][ni][rg];
        float gate = (__fdividef(yf * yf, a2 + w2f[ni] - 2.f * yf + 1e-6f) + bjf[ni]) * ysf;
        float yg = accg[mi][ni][rg];
        float u  = (__fdividef(yg * yg, a2 + w2g[ni] - 2.f * yg + 1e-6f) + bjg[ni]) * ysg;
        float out = gelu_t(u) * gate;
        p.mlp[(long)ii * 3072 + js[ni]] = f2bf(out);
        rsum += out * out;
      }
      #pragma unroll
      for (int o = 8; o; o >>= 1) rsum += __shfl_xor(rsum, o);
      if (l == 0) atomicAdd(&p.mrow2[ii], rsum);
    }
  }
}

// ---------------- flash attention: 64-row Q tiles, causal, prefetched -------
// (R4 best-measured version: staged K+V, dist-2, no setprio. Frozen.)
__global__ __launch_bounds__(256) void k_attn(const unsigned short* __restrict__ qb,
    const unsigned short* __restrict__ kb, const unsigned short* __restrict__ vb,
    unsigned short* __restrict__ ob, float* __restrict__ orow2) {
  __shared__ __align__(16) unsigned short Qs[4096];
  __shared__ __align__(16) unsigned short Ks[3][4096];
  __shared__ __align__(16) unsigned short Vs[3][4096];
  __shared__ __align__(16) unsigned short Ps[4096];
  const int tid = threadIdx.x, wave = tid >> 6, lane = tid & 63;
  const int quad = lane >> 4, l = lane & 15;
  const int g = xcd_swizzle(blockIdx.x, 16 * 24);
  const int bh = g % 24, qt = 15 - (g / 24);   // heavy q-tiles first
  const int b = bh / 12, hh = bh % 12;
  const int q0 = qt * 64;
  const f32x4 fzero = {0.f, 0.f, 0.f, 0.f};

  // hoisted K/V staging pointers (sequential jt; advance per stage_kv call)
  const int rkv = tid >> 3;                       // 0..31
  const int ckv = (tid & 7) ^ (rkv & 7);
  const unsigned short* kp0 = kb + ((long)bh * 1024 + rkv) * 64 + ckv * 8;
  const unsigned short* kp1 = kp0 + (long)32 * 64;
  const unsigned short* vp0 = vb + (long)bh * 65536 + (long)rkv * 1024 + ckv * 8;
  const unsigned short* vp1 = vp0 + (long)32 * 1024;

  auto stage_kv = [&](int s) {
    async16(kp0, &Ks[s][tid * 8]);
    async16(vp0, &Vs[s][tid * 8]);
    async16(kp1, &Ks[s][(tid + 256) * 8]);
    async16(vp1, &Vs[s][(tid + 256) * 8]);
    kp0 += 4096; kp1 += 4096;    // next 64 K-rows
    vp0 += 64;   vp1 += 64;      // next 64 t-columns
  };

  const unsigned short* qg = qb + ((long)bh * 1024 + q0) * 64;
  #pragma unroll
  for (int it = 0; it < 2; ++it) {
    int ci = tid + it * 256;
    int r = ci >> 3;
    int c = (ci & 7) ^ (r & 7);
    async16(qg + (long)r * 64 + c * 8, &Qs[ci * 8]);
  }
  stage_kv(0);
  if (qt >= 1) {
    stage_kv(1);
    asm volatile("s_waitcnt vmcnt(4)" ::: "memory");
  } else {
    asm volatile("s_waitcnt vmcnt(0)" ::: "memory");
  }
  __builtin_amdgcn_s_barrier();
  asm volatile("" ::: "memory");

  bf16x8 aq[2];
  #pragma unroll
  for (int ks = 0; ks < 2; ++ks)
    aq[ks] = *(const bf16x8*)&Qs[(wave * 16 + l) * 64 + (((ks * 4 + quad) ^ (l & 7)) * 8)];

  f32x4 O[4];
  float mi_[4], li[4];
  #pragma unroll
  for (int f = 0; f < 4; ++f) O[f] = fzero;
  #pragma unroll
  for (int r = 0; r < 4; ++r) { mi_[r] = -1e30f; li[r] = 0.f; }

  for (int jt = 0; jt <= qt; ++jt) {
    const int s = jt % 3;
    if (jt > 0) {
      if (jt + 1 <= qt) { asm volatile("s_waitcnt vmcnt(4)" ::: "memory"); }
      else              { asm volatile("s_waitcnt vmcnt(0)" ::: "memory"); }
      __builtin_amdgcn_s_barrier();
      asm volatile("" ::: "memory");
    }
    if (jt + 2 <= qt) stage_kv((jt + 2) % 3);

    f32x4 S[4];
    #pragma unroll
    for (int f = 0; f < 4; ++f) S[f] = fzero;
    #pragma unroll
    for (int ks = 0; ks < 2; ++ks) {
      #pragma unroll
      for (int f = 0; f < 4; ++f) {
        bf16x8 bk = *(const bf16x8*)&Ks[s][(f * 16 + l) * 64 + (((ks * 4 + quad) ^ (l & 7)) * 8)];
        S[f] = __builtin_amdgcn_mfma_f32_16x16x32_bf16(aq[ks], bk, S[f], 0, 0, 0);
      }
    }
    const bool diag = (jt == qt);
    #pragma unroll
    for (int f = 0; f < 4; ++f)
      #pragma unroll
      for (int r = 0; r < 4; ++r) {
        float v = S[f][r] * 0.125f;
        if (diag && (f * 16 + l > wave * 16 + quad * 4 + r)) v = -1e30f;
        S[f][r] = v;
      }
    #pragma unroll
    for (int r = 0; r < 4; ++r) {
      float mx = fmaxf(fmaxf(S[0][r], S[1][r]), fmaxf(S[2][r], S[3][r]));
      #pragma unroll
      for (int o = 8; o; o >>= 1) mx = fmaxf(mx, __shfl_xor(mx, o));
      float mnew = fmaxf(mi_[r], mx);
      float alr = __expf(mi_[r] - mnew);
      float sum = 0.f;
      #pragma unroll
      for (int f = 0; f < 4; ++f) {
        float e = __expf(S[f][r] - mnew);
        S[f][r] = e;
        sum += e;
      }
      #pragma unroll
      for (int o = 8; o; o >>= 1) sum += __shfl_xor(sum, o);
      li[r] = li[r] * alr + sum;
      #pragma unroll
      for (int f = 0; f < 4; ++f) O[f][r] *= alr;
      mi_[r] = mnew;
    }
    #pragma unroll
    for (int f = 0; f < 4; ++f)
      #pragma unroll
      for (int r = 0; r < 4; ++r) {
        int i = quad * 4 + r;
        int j = f * 16 + l;
        int pch = (j >> 3) ^ (i & 7);
        Ps[wave * 1024 + i * 64 + pch * 8 + (j & 7)] = f2bf(S[f][r]);
      }
    #pragma unroll
    for (int ks = 0; ks < 2; ++ks) {
      bf16x8 ap = *(const bf16x8*)&Ps[wave * 1024 + l * 64 + (((ks * 4 + quad) ^ (l & 7)) * 8)];
      #pragma unroll
      for (int f = 0; f < 4; ++f) {
        bf16x8 bv = *(const bf16x8*)&Vs[s][(f * 16 + l) * 64 + (((ks * 4 + quad) ^ (l & 7)) * 8)];
        O[f] = __builtin_amdgcn_mfma_f32_16x16x32_bf16(ap, bv, O[f], 0, 0, 0);
      }
    }
  }
  float inv[4];
  #pragma unroll
  for (int r = 0; r < 4; ++r) inv[r] = __fdividef(1.f, li[r]);
  #pragma unroll
  for (int f = 0; f < 4; ++f)
    #pragma unroll
    for (int r = 0; r < 4; ++r) {
      int t = q0 + wave * 16 + quad * 4 + r;
      int dd = f * 16 + l;
      ob[((long)(b * 1024 + t) * 12 + hh) * 64 + dd] = f2bf(O[f][r] * inv[r]);  // (B,T,H,D)
    }
  #pragma unroll
  for (int r = 0; r < 4; ++r) {
    float rsum = 0.f;
    #pragma unroll
    for (int f = 0; f < 4; ++f) { float v = O[f][r] * inv[r]; rsum += v * v; }
    #pragma unroll
    for (int o = 8; o; o >>= 1) rsum += __shfl_xor(rsum, o);
    if (l == 0) {
      int t = q0 + wave * 16 + quad * 4 + r;
      atomicAdd(&orow2[b * 1024 + t], rsum);
    }
  }
}

// ---------------- host ------------------------------------------------------
extern "C" void kernel_launch(void* const* d_in, const int* in_sizes, int n_in,
                              void* d_out, int out_size, void* d_ws, size_t ws_size,
                              hipStream_t stream) {
  (void)in_sizes; (void)n_in; (void)out_size;
  char* w = (char*)d_ws;
  size_t off = 0;
  auto alloc = [&](size_t bytes) -> void* {
    void* p = w + off;
    off = (off + bytes + 255) & ~(size_t)255;
    return p;
  };
  float* rope            = (float*)alloc(65536 * 4);
  unsigned short* wtqkv  = (unsigned short*)alloc((size_t)2304 * 768 * 2);
  unsigned short* wtao   = (unsigned short*)alloc((size_t)768 * 768 * 2);
  unsigned short* wtfc   = (unsigned short*)alloc((size_t)3072 * 768 * 2);
  unsigned short* wtgate = (unsigned short*)alloc((size_t)3072 * 768 * 2);
  unsigned short* wtproj = (unsigned short*)alloc((size_t)768 * 3072 * 2);
  float* zeroed          = (float*)alloc(14080 * 4);   // wcol2(9984) + orow2(2048) + mrow2(2048)
  unsigned short* h1     = (unsigned short*)alloc((size_t)2048 * 768 * 2);
  float* hrow1           = (float*)alloc(2048 * 4);
  unsigned short* qbuf   = (unsigned short*)alloc((size_t)2048 * 768 * 2);
  unsigned short* kbuf   = (unsigned short*)alloc((size_t)2048 * 768 * 2);
  unsigned short* vbuf   = (unsigned short*)alloc((size_t)2048 * 768 * 2);
  unsigned short* obuf   = (unsigned short*)alloc((size_t)2048 * 768 * 2);
  float* xo              = (float*)alloc((size_t)2048 * 768 * 4);
  unsigned short* h2     = (unsigned short*)alloc((size_t)2048 * 768 * 2);
  float* hrow2           = (float*)alloc(2048 * 4);
  unsigned short* mlp    = (unsigned short*)alloc((size_t)2048 * 3072 * 2);
  unsigned short* slabs  = (unsigned short*)alloc((size_t)4 * 2048 * 768 * 2);  // bf16 split-K partials
  if (off > ws_size) return;

  float* wcol2  = zeroed;
  float* orow2  = zeroed + 9984;
  float* mrow2  = zeroed + 9984 + 2048;
  float* c_qkv  = wcol2 + 0;
  float* c_ao   = wcol2 + 2304;
  float* c_fc   = wcol2 + 3072;
  float* c_gate = wcol2 + 6144;
  float* c_proj = wcol2 + 9216;

  const float* xin = (const float*)d_in[0];

  hipMemsetAsync(zeroed, 0, 14080 * 4, stream);

  PrepArgs pa;
  pa.rope = rope;
  pa.W[0] = (const float*)d_in[3];  pa.Wt[0] = wtqkv;  pa.cn[0] = c_qkv;  pa.N[0] = 2304;
  pa.W[1] = (const float*)d_in[6];  pa.Wt[1] = wtao;   pa.cn[1] = c_ao;   pa.N[1] = 768;
  pa.W[2] = (const float*)d_in[10]; pa.Wt[2] = wtfc;   pa.cn[2] = c_fc;   pa.N[2] = 3072;
  pa.W[3] = (const float*)d_in[13]; pa.Wt[3] = wtgate; pa.cn[3] = c_gate; pa.N[3] = 3072;
  pa.W[4] = (const float*)d_in[16]; pa.Wt[4] = wtproj; pa.cn[4] = c_proj; pa.N[4] = 768;
  // 64x64 tiles: qkv 36x12=432, ao 12x12=144, fc 48x12=576, gate 576, proj 12x48=576
  pa.off[0] = 0; pa.off[1] = 432; pa.off[2] = 576; pa.off[3] = 1152;
  pa.off[4] = 1728; pa.off[5] = 2304;
  pa.x = xin; pa.g1s = (const float*)d_in[2]; pa.h1 = h1; pa.hrow1 = hrow1;
  k_prep<<<4608, 256, 0, stream>>>(pa);

  GemmArgs gq = {};
  gq.A = h1; gq.Bt = wtqkv; gq.arow2 = hrow1; gq.wcol2 = c_qkv;
  gq.bias = (const float*)d_in[4]; gq.alpha = (const float*)d_in[5];
  gq.N = 2304; gq.ks = 768;
  gq.rope = rope; gq.qo = qbuf; gq.ko = kbuf; gq.vo = vbuf;
  k_gemm<M_QKV, 24, 32, 18, 1><<<576, 256, 0, stream>>>(gq);

  k_attn<<<384, 256, 0, stream>>>(qbuf, kbuf, vbuf, obuf, orow2);

  GemmArgs ga = {};
  ga.A = obuf; ga.Bt = wtao; ga.arow2 = orow2; ga.wcol2 = c_ao;
  ga.bias = (const float*)d_in[7]; ga.alpha = (const float*)d_in[8];
  ga.N = 768; ga.ks = 768;
  ga.xf = xin; ga.xo = xo;
  k_gemm_ao<<<384, 256, 0, stream>>>(ga);

  k_ln<<<2048, 256, 0, stream>>>(xo, (const float*)d_in[9], h2, hrow2);

  MlpArgs gm = {};
  gm.A = h2; gm.Bf = wtfc; gm.Bg = wtgate; gm.arow2 = hrow2;
  gm.w2f = c_fc; gm.w2g = c_gate;
  gm.bf = (const float*)d_in[11]; gm.bg = (const float*)d_in[14];
  gm.af_ = (const float*)d_in[12]; gm.ag_ = (const float*)d_in[15];
  gm.mlp = mlp; gm.mrow2 = mrow2;
  k_mlp<<<768, 256, 0, stream>>>(gm);

  GemmArgs gp = {};
  gp.A = mlp; gp.Bt = wtproj;
  gp.N = 768; gp.ks = 3072;
  gp.partb = slabs;
  k_gemm<M_PART, 24, 32, 6, 4><<<768, 256, 0, stream>>>(gp);

  EpiArgs ge = {};
  ge.slab = slabs; ge.arow2 = mrow2; ge.wcol2 = c_proj;
  ge.bias = (const float*)d_in[17]; ge.alpha = (const float*)d_in[18];
  ge.xo = xo; ge.outf = (float*)d_out;
  k_proj_epi<<<1536, 256, 0, stream>>>(ge);
}

// Round 11
// 259.757 us; speedup vs baseline: 1.0799x; 1.0071x over previous
//
#include <hip/hip_runtime.h>
#include <cstdint>

#define DEVFN static __device__ __forceinline__

typedef __bf16 bf16x8 __attribute__((ext_vector_type(8)));
typedef float f32x4 __attribute__((ext_vector_type(4)));
typedef unsigned short us4 __attribute__((ext_vector_type(4)));

DEVFN unsigned short f2bf(float f) {
  unsigned u = __float_as_uint(f);
  u += 0x7fffu + ((u >> 16) & 1u);           // round-to-nearest-even
  return (unsigned short)(u >> 16);
}
DEVFN float bf2f(unsigned short h) { return __uint_as_float(((unsigned)h) << 16); }
DEVFN void async16(const void* g, void* l) {
  __builtin_amdgcn_global_load_lds((__attribute__((address_space(1))) const void*)g,
                                   (__attribute__((address_space(3))) void*)l, 16, 0, 0);
}
// gelu(tanh approx) == u * sigmoid(2z), z = 0.79788456*(u+0.044715u^3)  (exact identity)
DEVFN float gelu_t(float u) {
  float z = 0.7978845608028654f * (u + 0.044715f * u * u * u);
  float zc = fminf(fmaxf(z, -15.f), 15.f);
  float e = __expf(2.f * zc);
  return u * __fdividef(e, e + 1.f);
}
// XCD swizzle: lin%8 = XCD class; give each XCD a contiguous slice of g-space
DEVFN int xcd_swizzle(int lin, int total) {
  return (lin & 7) * (total >> 3) + (lin >> 3);
}

// ---------------- merged prep: rope + 5 transposes (64x64) + LN1 ------------
struct PrepArgs {
  float* rope;
  const float* W[5]; unsigned short* Wt[5]; float* cn[5];
  int N[5]; int off[6];
  const float* x; const float* g1s; unsigned short* h1; float* hrow1;
};
__global__ __launch_bounds__(256) void k_prep(PrepArgs a) {
  __shared__ float tile[64][65];
  __shared__ float part[4][64];
  __shared__ float red[12];
  const int bid = blockIdx.x, tid = threadIdx.x;
  if (bid < 256) {                       // rope table
    int g = bid * 256 + tid;
    int t = g >> 6, dd = g & 63, i = dd & 31;
    float fr = __expf(-0.2878231366242558f * (float)i);   // ln(1e4)/32
    float ang = (float)t * fr;
    a.rope[g] = (dd < 32) ? cosf(ang) : sinf(ang);
  } else if (bid < 2560) {               // weight transpose + col sq-norms
    int lin = bid - 256;
    int e = 0;
    while (lin >= a.off[e + 1]) ++e;
    int local = lin - a.off[e];
    const int N = a.N[e];
    int nbx = N >> 6;
    int tn = local % nbx, tk = local / nbx;
    const float* W = a.W[e];
    unsigned short* Wt = a.Wt[e];
    float* cn = a.cn[e];
    const int K = (e == 4) ? 3072 : 768;
    int tx = tid & 63, ty = tid >> 6;    // ty 0..3
    float acc = 0.f;
    #pragma unroll
    for (int j = 0; j < 16; ++j) {
      int r = ty + j * 4;                // 0..63
      float v = W[(long)(tk * 64 + r) * N + tn * 64 + tx];
      tile[r][tx] = v;
      acc += v * v;
    }
    part[ty][tx] = acc;
    __syncthreads();
    #pragma unroll
    for (int j = 0; j < 16; ++j) {
      int rr = ty + j * 4;
      Wt[(long)(tn * 64 + rr) * K + tk * 64 + tx] = f2bf(tile[tx][rr]);
    }
    if (ty == 0) {
      float s = part[0][tx] + part[1][tx] + part[2][tx] + part[3][tx];
      atomicAdd(&cn[tn * 64 + tx], s);
    }
  } else {                               // LN1
    int row = bid - 2560;
    const float* xr = a.x + (long)row * 768;
    float v0 = xr[tid], v1 = xr[tid + 256], v2 = xr[tid + 512];
    float s = v0 + v1 + v2;
    float ss = v0 * v0 + v1 * v1 + v2 * v2;
    #pragma unroll
    for (int o = 32; o; o >>= 1) { s += __shfl_xor(s, o); ss += __shfl_xor(ss, o); }
    int wv = tid >> 6;
    if ((tid & 63) == 0) { red[wv] = s; red[wv + 4] = ss; }
    __syncthreads();
    s = red[0] + red[1] + red[2] + red[3];
    ss = red[4] + red[5] + red[6] + red[7];
    float mu = s * (1.f / 768.f);
    float var = ss * (1.f / 768.f) - mu * mu;
    float rs = rsqrtf(var + 1e-6f);
    float h0 = (v0 - mu) * rs * a.g1s[tid];
    float h1 = (v1 - mu) * rs * a.g1s[tid + 256];
    float h2 = (v2 - mu) * rs * a.g1s[tid + 512];
    unsigned short* hr = a.h1 + (long)row * 768;
    hr[tid] = f2bf(h0); hr[tid + 256] = f2bf(h1); hr[tid + 512] = f2bf(h2);
    float p = h0 * h0 + h1 * h1 + h2 * h2;
    #pragma unroll
    for (int o = 32; o; o >>= 1) p += __shfl_xor(p, o);
    if ((tid & 63) == 0) red[8 + wv] = p;
    __syncthreads();
    if (tid == 0) a.hrow1[row] = red[8] + red[9] + red[10] + red[11];
  }
}

// ---------------- layernorm (f32 in) -> bf16 h + row sum(h^2) ---------------
__global__ __launch_bounds__(256) void k_ln(const float* __restrict__ x,
    const float* __restrict__ g, unsigned short* __restrict__ h, float* __restrict__ row2) {
  int row = blockIdx.x, tid = threadIdx.x;
  const float* xr = x + (long)row * 768;
  float v0 = xr[tid], v1 = xr[tid + 256], v2 = xr[tid + 512];
  float s = v0 + v1 + v2;
  float ss = v0 * v0 + v1 * v1 + v2 * v2;
  #pragma unroll
  for (int o = 32; o; o >>= 1) { s += __shfl_xor(s, o); ss += __shfl_xor(ss, o); }
  __shared__ float red[12];
  int wv = tid >> 6;
  if ((tid & 63) == 0) { red[wv] = s; red[wv + 4] = ss; }
  __syncthreads();
  s = red[0] + red[1] + red[2] + red[3];
  ss = red[4] + red[5] + red[6] + red[7];
  float mu = s * (1.f / 768.f);
  float var = ss * (1.f / 768.f) - mu * mu;
  float rs = rsqrtf(var + 1e-6f);
  float h0 = (v0 - mu) * rs * g[tid];
  float h1 = (v1 - mu) * rs * g[tid + 256];
  float h2 = (v2 - mu) * rs * g[tid + 512];
  unsigned short* hr = h + (long)row * 768;
  hr[tid] = f2bf(h0); hr[tid + 256] = f2bf(h1); hr[tid + 512] = f2bf(h2);
  float p = h0 * h0 + h1 * h1 + h2 * h2;
  #pragma unroll
  for (int o = 32; o; o >>= 1) p += __shfl_xor(p, o);
  if ((tid & 63) == 0) red[8 + wv] = p;
  __syncthreads();
  if (tid == 0) row2[row] = red[8] + red[9] + red[10] + red[11];
}

// ---------------- yat GEMM: 64x128 tile, 3-buffer distance-2, XCD swizzle ---
constexpr int M_QKV = 0, M_AO = 1, M_PART = 2;

struct GemmArgs {
  const unsigned short* A; const unsigned short* Bt;
  const float* arow2; const float* wcol2; const float* bias; const float* alpha;
  int N; int ks;
  const float* rope;                                    // QKV
  unsigned short* qo; unsigned short* ko; unsigned short* vo;  // QKV
  const float* xf; float* xo;                           // AO: residual in/out (f32)
  unsigned short* partb;                                // PART: bf16 slab base
};

template <int MODE, int NI, int NBM, int NBN, int NZ>
__global__ __launch_bounds__(256, 4) void k_gemm(GemmArgs p) {
  __shared__ __align__(16) unsigned short As[3][2048];   // 64 x 32
  __shared__ __align__(16) unsigned short Bs[3][4096];   // 128 x 32
  const int tid = threadIdx.x, wave = tid >> 6, lane = tid & 63;
  const int quad = lane >> 4, l = lane & 15;
  constexpr int TOTAL = NBM * NBN * NZ;
  const int g = xcd_swizzle(blockIdx.x, TOTAL);
  const int bm = (g % NBM) * 64;
  const int rest = g / NBM;
  const int bn = (rest % NBN) * 128;
  const int z = rest / NBN;
  const int kb = z * (NI * 32);
  const int ks = p.ks;
  const int wm = (wave & 1) * 32, wn = (wave >> 1) * 64;
  const f32x4 fzero = {0.f, 0.f, 0.f, 0.f};
  f32x4 acc[2][4];
  #pragma unroll
  for (int i = 0; i < 2; ++i)
    #pragma unroll
    for (int j = 0; j < 4; ++j) acc[i][j] = fzero;
  const int sw = (l >> 1) & 3;

  // hoisted per-thread staging pointers (advance +32 elements per stage call)
  const int r0 = tid >> 2;
  const int c0 = (tid & 3) ^ ((r0 >> 1) & 3);
  const unsigned short* ap  = p.A  + (long)(bm + r0) * ks + kb + c0 * 8;
  const unsigned short* bp0 = p.Bt + (long)(bn + r0) * ks + kb + c0 * 8;
  const unsigned short* bp1 = bp0 + (long)64 * ks;

  auto stage = [&](int s) {
    async16(ap,  &As[s][tid * 8]);
    async16(bp0, &Bs[s][tid * 8]);
    async16(bp1, &Bs[s][(tid + 256) * 8]);
    ap += 32; bp0 += 32; bp1 += 32;
  };
  auto compute = [&](int s) {
    bf16x8 af[2], bfv[4];
    #pragma unroll
    for (int mi = 0; mi < 2; ++mi)
      af[mi] = *(const bf16x8*)&As[s][(wm + mi * 16 + l) * 32 + ((quad ^ sw) * 8)];
    #pragma unroll
    for (int ni = 0; ni < 4; ++ni)
      bfv[ni] = *(const bf16x8*)&Bs[s][(wn + ni * 16 + l) * 32 + ((quad ^ sw) * 8)];
    #pragma unroll
    for (int mi = 0; mi < 2; ++mi)
      #pragma unroll
      for (int ni = 0; ni < 4; ++ni)
        acc[mi][ni] = __builtin_amdgcn_mfma_f32_16x16x32_bf16(af[mi], bfv[ni], acc[mi][ni], 0, 0, 0);
  };
  auto iter = [&](int s, int i) {
    if (i + 1 >= NI) { asm volatile("s_waitcnt vmcnt(0)" ::: "memory"); }
    else             { asm volatile("s_waitcnt vmcnt(3)" ::: "memory"); }
    __builtin_amdgcn_s_barrier();
    asm volatile("" ::: "memory");
    if (i + 2 < NI) stage(s == 0 ? 2 : s - 1);
    compute(s);
  };

  stage(0);
  stage(1);
  int i = 0;
  while (i < NI) {          // NI % 3 == 0
    iter(0, i); ++i;
    iter(1, i); ++i;
    iter(2, i); ++i;
  }

  if constexpr (MODE == M_PART) {
    unsigned short* slab = p.partb + (long)z * (2048 * 768);
    #pragma unroll
    for (int ni = 0; ni < 4; ++ni) {
      const int j = bn + wn + ni * 16 + l;
      #pragma unroll
      for (int mi = 0; mi < 2; ++mi) {
        const int i0 = bm + wm + mi * 16 + quad * 4;
        #pragma unroll
        for (int rg = 0; rg < 4; ++rg)
          slab[(long)(i0 + rg) * 768 + j] = f2bf(acc[mi][ni][rg]);
      }
    }
  } else {
    const float al = p.alpha[0];
    const float nn = (float)p.N;
    const float ys = powf(sqrtf(nn) / log1pf(nn), al);
    #pragma unroll
    for (int ni = 0; ni < 4; ++ni) {
      const int j = bn + wn + ni * 16 + l;
      const float w2 = p.wcol2[j];
      const float bj = p.bias[j];
      #pragma unroll
      for (int mi = 0; mi < 2; ++mi) {
        const int i0 = bm + wm + mi * 16 + quad * 4;
        #pragma unroll
        for (int rg = 0; rg < 4; ++rg) {
          const float y = acc[mi][ni][rg];
          const float dist = p.arow2[i0 + rg] + w2 - 2.f * y + 1e-6f;
          long idx = (long)(i0 + rg) * 768 + j;
          p.xo[idx] = p.xf[idx] + (__fdividef(y * y, dist) + bj) * ys;
        }
      }
    }
  }
}

// ---- 64x64-tile yat GEMM (AO + QKV epilogues): 4 blocks/CU co-residency ----
// R8/R9 proved this structure on AO; R11 extends it to QKV (576 blocks at
// 2.25/CU had 3-vs-2 tile imbalance -> 1152 balanced half-size blocks at
// 4/CU). Same 3-buffer dist-2 schedule; 2 async16/stage -> steady vmcnt(2).
template <int MODE, int NBM, int NBN>
__global__ __launch_bounds__(256, 4) void k_gemm64(GemmArgs p) {
  constexpr int NI = 24;
  __shared__ __align__(16) unsigned short As[3][2048];   // 64 x 32
  __shared__ __align__(16) unsigned short Bs[3][2048];   // 64 x 32
  const int tid = threadIdx.x, wave = tid >> 6, lane = tid & 63;
  const int quad = lane >> 4, l = lane & 15;
  const int g = xcd_swizzle(blockIdx.x, NBM * NBN);
  const int bm = (g % NBM) * 64;
  const int bn = (g / NBM) * 64;
  const int ks = p.ks;
  const int wm = (wave & 1) * 32, wn = (wave >> 1) * 32;
  const f32x4 fzero = {0.f, 0.f, 0.f, 0.f};
  f32x4 acc[2][2];
  #pragma unroll
  for (int i = 0; i < 2; ++i)
    #pragma unroll
    for (int j = 0; j < 2; ++j) acc[i][j] = fzero;
  const int sw = (l >> 1) & 3;

  const int r0 = tid >> 2;
  const int c0 = (tid & 3) ^ ((r0 >> 1) & 3);
  const unsigned short* ap = p.A  + (long)(bm + r0) * ks + c0 * 8;
  const unsigned short* bp = p.Bt + (long)(bn + r0) * ks + c0 * 8;

  auto stage = [&](int s) {
    async16(ap, &As[s][tid * 8]);
    async16(bp, &Bs[s][tid * 8]);
    ap += 32; bp += 32;
  };
  auto compute = [&](int s) {
    bf16x8 af[2], bfv[2];
    #pragma unroll
    for (int mi = 0; mi < 2; ++mi)
      af[mi] = *(const bf16x8*)&As[s][(wm + mi * 16 + l) * 32 + ((quad ^ sw) * 8)];
    #pragma unroll
    for (int ni = 0; ni < 2; ++ni)
      bfv[ni] = *(const bf16x8*)&Bs[s][(wn + ni * 16 + l) * 32 + ((quad ^ sw) * 8)];
    #pragma unroll
    for (int mi = 0; mi < 2; ++mi)
      #pragma unroll
      for (int ni = 0; ni < 2; ++ni)
        acc[mi][ni] = __builtin_amdgcn_mfma_f32_16x16x32_bf16(af[mi], bfv[ni], acc[mi][ni], 0, 0, 0);
  };
  auto iter = [&](int s, int i) {
    if (i + 1 >= NI) { asm volatile("s_waitcnt vmcnt(0)" ::: "memory"); }
    else             { asm volatile("s_waitcnt vmcnt(2)" ::: "memory"); }
    __builtin_amdgcn_s_barrier();
    asm volatile("" ::: "memory");
    if (i + 2 < NI) stage((i + 2) % 3);
    compute(s);
  };

  stage(0);
  stage(1);
  int i = 0;
  while (i < NI) {          // NI % 3 == 0
    iter(0, i); ++i;
    iter(1, i); ++i;
    iter(2, i); ++i;
  }

  const float al = p.alpha[0];
  const float nn = (float)p.N;
  const float ys = powf(sqrtf(nn) / log1pf(nn), al);
  #pragma unroll
  for (int ni = 0; ni < 2; ++ni) {
    const int j = bn + wn + ni * 16 + l;
    const float w2 = p.wcol2[j];
    const float bj = p.bias[j];
    int s3 = 0, hh = 0, dd = 0;
    if constexpr (MODE == M_QKV) { s3 = j / 768; int rem = j - s3 * 768; hh = rem >> 6; dd = rem & 63; }
    #pragma unroll
    for (int mi = 0; mi < 2; ++mi) {
      const int i0 = bm + wm + mi * 16 + quad * 4;
      float vv[4];
      #pragma unroll
      for (int rg = 0; rg < 4; ++rg) {
        const float y = acc[mi][ni][rg];
        const float dist = p.arow2[i0 + rg] + w2 - 2.f * y + 1e-6f;
        vv[rg] = (__fdividef(y * y, dist) + bj) * ys;
      }
      if constexpr (MODE == M_QKV) {
        int b = i0 >> 10, t0 = i0 & 1023;
        if (s3 == 2) {
          us4 pk = {f2bf(vv[0]), f2bf(vv[1]), f2bf(vv[2]), f2bf(vv[3])};
          *(us4*)&p.vo[((long)(b * 12 + hh) * 64 + dd) * 1024 + t0] = pk;    // V^T (B,H,D,T)
        } else {
          unsigned short* dst = (s3 == 0) ? p.qo : p.ko;                     // (B,H,T,D)
          #pragma unroll
          for (int rg = 0; rg < 4; ++rg) {
            float ro = p.rope[(t0 + rg) * 64 + dd];
            dst[((long)(b * 12 + hh) * 1024 + t0 + rg) * 64 + dd] = f2bf(vv[rg] * ro);
          }
        }
      } else {  // M_AO
        #pragma unroll
        for (int rg = 0; rg < 4; ++rg) {
          const float y = acc[mi][ni][rg];
          long idx = (long)(i0 + rg) * 768 + j;
          p.xo[idx] = p.xf[idx] + vv[rg];
          (void)y;
        }
      }
    }
  }
}

// ---------------- PROJ reduce (4 bf16 slabs) + yat epilogue + residual ------
struct EpiArgs {
  const unsigned short* slab; const float* arow2; const float* wcol2;
  const float* bias; const float* alpha; const float* xo; float* outf;
};
__global__ __launch_bounds__(256) void k_proj_epi(EpiArgs p) {
  int g = blockIdx.x * 256 + threadIdx.x;   // 393216 = 2048*768/4
  int i = g / 192, jv = (g - i * 192) * 4;
  long base = (long)i * 768 + jv;
  f32x4 y = {0.f, 0.f, 0.f, 0.f};
  #pragma unroll
  for (int z = 0; z < 4; ++z) {
    us4 s4 = *(const us4*)(p.slab + (long)z * 1572864 + base);
    #pragma unroll
    for (int c = 0; c < 4; ++c) y[c] += bf2f(s4[c]);
  }
  const float a2 = p.arow2[i];
  const float ys = powf(sqrtf(768.f) / log1pf(768.f), p.alpha[0]);
  f32x4 xo4 = *(const f32x4*)(p.xo + base);
  f32x4 out;
  #pragma unroll
  for (int c = 0; c < 4; ++c) {
    float yy = y[c];
    float dist = a2 + p.wcol2[jv + c] - 2.f * yy + 1e-6f;
    out[c] = xo4[c] + (__fdividef(yy * yy, dist) + p.bias[jv + c]) * ys;
  }
  *(f32x4*)(p.outf + base) = out;
}

// ---- merged FC+GATE yat GEMM: 128x64 tile, A+B all LDS-staged, 3-buffer ----
// (R4 best-measured version: 43.6 us. Structure-limited; frozen.)
struct MlpArgs {
  const unsigned short* A; const unsigned short* Bf; const unsigned short* Bg;
  const float* arow2; const float* w2f; const float* w2g;
  const float* bf; const float* bg; const float* af_; const float* ag_;
  unsigned short* mlp; float* mrow2;
};

__global__ __launch_bounds__(256, 3) void k_mlp(MlpArgs p) {
  constexpr int NI = 24, K = 768;
  __shared__ __align__(16) unsigned short As[3][4096];    // 128 x 32
  __shared__ __align__(16) unsigned short Bfs[3][2048];   // 64 x 32
  __shared__ __align__(16) unsigned short Bgs[3][2048];   // 64 x 32
  const int tid = threadIdx.x, wave = tid >> 6, lane = tid & 63;
  const int quad = lane >> 4, l = lane & 15;
  const int g = xcd_swizzle(blockIdx.x, 16 * 48);
  const int bm = (g % 16) * 128, bn = (g / 16) * 64;
  const int wm = wave * 32;                // 4 waves x 32 rows; all share 64 cols
  const f32x4 fzero = {0.f, 0.f, 0.f, 0.f};
  f32x4 accf[2][4], accg[2][4];
  #pragma unroll
  for (int i = 0; i < 2; ++i)
    #pragma unroll
    for (int j = 0; j < 4; ++j) { accf[i][j] = fzero; accg[i][j] = fzero; }
  const int sw = (l >> 1) & 3;

  // hoisted per-thread staging pointers (advance +32 elements per stage call)
  const int r0 = tid >> 2;
  const int c0 = (tid & 3) ^ ((r0 >> 1) & 3);
  const unsigned short* ap0 = p.A  + (long)(bm + r0) * K + c0 * 8;
  const unsigned short* ap1 = ap0 + (long)64 * K;
  const unsigned short* bfp = p.Bf + (long)(bn + r0) * K + c0 * 8;
  const unsigned short* bgp = p.Bg + (long)(bn + r0) * K + c0 * 8;

  auto stage = [&](int s) {
    async16(ap0, &As[s][tid * 8]);
    async16(ap1, &As[s][(tid + 256) * 8]);
    async16(bfp, &Bfs[s][tid * 8]);
    async16(bgp, &Bgs[s][tid * 8]);
    ap0 += 32; ap1 += 32; bfp += 32; bgp += 32;
  };
  auto compute = [&](int s) {
    bf16x8 af[2], bff[4], bfg[4];
    #pragma unroll
    for (int mi = 0; mi < 2; ++mi)
      af[mi] = *(const bf16x8*)&As[s][(wm + mi * 16 + l) * 32 + ((quad ^ sw) * 8)];
    #pragma unroll
    for (int ni = 0; ni < 4; ++ni) {
      bff[ni] = *(const bf16x8*)&Bfs[s][(ni * 16 + l) * 32 + ((quad ^ sw) * 8)];
      bfg[ni] = *(const bf16x8*)&Bgs[s][(ni * 16 + l) * 32 + ((quad ^ sw) * 8)];
    }
    __builtin_amdgcn_s_setprio(1);
    #pragma unroll
    for (int ni = 0; ni < 4; ++ni) {
      accf[0][ni] = __builtin_amdgcn_mfma_f32_16x16x32_bf16(af[0], bff[ni], accf[0][ni], 0, 0, 0);
      accg[0][ni] = __builtin_amdgcn_mfma_f32_16x16x32_bf16(af[0], bfg[ni], accg[0][ni], 0, 0, 0);
      accf[1][ni] = __builtin_amdgcn_mfma_f32_16x16x32_bf16(af[1], bff[ni], accf[1][ni], 0, 0, 0);
      accg[1][ni] = __builtin_amdgcn_mfma_f32_16x16x32_bf16(af[1], bfg[ni], accg[1][ni], 0, 0, 0);
    }
    __builtin_amdgcn_s_setprio(0);
  };
  auto iter = [&](int s, int i) {
    if (i + 1 >= NI) { asm volatile("s_waitcnt vmcnt(0)" ::: "memory"); }
    else             { asm volatile("s_waitcnt vmcnt(4)" ::: "memory"); }
    __builtin_amdgcn_s_barrier();
    asm volatile("" ::: "memory");
    if (i + 2 < NI) stage((i + 2) % 3);
    compute(s);
  };

  stage(0);
  stage(1);
  int i = 0;
  while (i < NI) {          // NI % 3 == 0
    iter(0, i); ++i;
    iter(1, i); ++i;
    iter(2, i); ++i;
  }

  const float ysf = powf(sqrtf(3072.f) / log1pf(3072.f), p.af_[0]);
  const float ysg = powf(sqrtf(3072.f) / log1pf(3072.f), p.ag_[0]);
  float w2f[4], w2g[4], bjf[4], bjg[4]; int js[4];
  #pragma unroll
  for (int ni = 0; ni < 4; ++ni) {
    int j = bn + ni * 16 + l;
    js[ni] = j; w2f[ni] = p.w2f[j]; w2g[ni] = p.w2g[j]; bjf[ni] = p.bf[j]; bjg[ni] = p.bg[j];
  }
  #pragma unroll
  for (int mi = 0; mi < 2; ++mi) {
    #pragma unroll
    for (int rg = 0; rg < 4; ++rg) {
      const int ii = bm + wm + mi * 16 + quad * 4 + rg;
      const float a2 = p.arow2[ii];
      float rsum = 0.f;
      #pragma unroll
      for (int ni = 0; ni < 4; ++ni) {
        float yf = accf[mi][ni][rg];
        float gate = (__fdividef(yf * yf, a2 + w2f[ni] - 2.f * yf + 1e-6f) + bjf[ni]) * ysf;
        float yg = accg[mi][ni][rg];
        float u  = (__fdividef(yg * yg, a2 + w2g[ni] - 2.f * yg + 1e-6f) + bjg[ni]) * ysg;
        float out = gelu_t(u) * gate;
        p.mlp[(long)ii * 3072 + js[ni]] = f2bf(out);
        rsum += out * out;
      }
      #pragma unroll
      for (int o = 8; o; o >>= 1) rsum += __shfl_xor(rsum, o);
      if (l == 0) atomicAdd(&p.mrow2[ii], rsum);
    }
  }
}

// ---------------- flash attention: 64-row Q tiles, causal, prefetched -------
// (R4 best-measured version: staged K+V, dist-2, no setprio. Frozen.)
__global__ __launch_bounds__(256) void k_attn(const unsigned short* __restrict__ qb,
    const unsigned short* __restrict__ kb, const unsigned short* __restrict__ vb,
    unsigned short* __restrict__ ob, float* __restrict__ orow2) {
  __shared__ __align__(16) unsigned short Qs[4096];
  __shared__ __align__(16) unsigned short Ks[3][4096];
  __shared__ __align__(16) unsigned short Vs[3][4096];
  __shared__ __align__(16) unsigned short Ps[4096];
  const int tid = threadIdx.x, wave = tid >> 6, lane = tid & 63;
  const int quad = lane >> 4, l = lane & 15;
  const int g = xcd_swizzle(blockIdx.x, 16 * 24);
  const int bh = g % 24, qt = 15 - (g / 24);   // heavy q-tiles first
  const int b = bh / 12, hh = bh % 12;
  const int q0 = qt * 64;
  const f32x4 fzero = {0.f, 0.f, 0.f, 0.f};

  // hoisted K/V staging pointers (sequential jt; advance per stage_kv call)
  const int rkv = tid >> 3;                       // 0..31
  const int ckv = (tid & 7) ^ (rkv & 7);
  const unsigned short* kp0 = kb + ((long)bh * 1024 + rkv) * 64 + ckv * 8;
  const unsigned short* kp1 = kp0 + (long)32 * 64;
  const unsigned short* vp0 = vb + (long)bh * 65536 + (long)rkv * 1024 + ckv * 8;
  const unsigned short* vp1 = vp0 + (long)32 * 1024;

  auto stage_kv = [&](int s) {
    async16(kp0, &Ks[s][tid * 8]);
    async16(vp0, &Vs[s][tid * 8]);
    async16(kp1, &Ks[s][(tid + 256) * 8]);
    async16(vp1, &Vs[s][(tid + 256) * 8]);
    kp0 += 4096; kp1 += 4096;    // next 64 K-rows
    vp0 += 64;   vp1 += 64;      // next 64 t-columns
  };

  const unsigned short* qg = qb + ((long)bh * 1024 + q0) * 64;
  #pragma unroll
  for (int it = 0; it < 2; ++it) {
    int ci = tid + it * 256;
    int r = ci >> 3;
    int c = (ci & 7) ^ (r & 7);
    async16(qg + (long)r * 64 + c * 8, &Qs[ci * 8]);
  }
  stage_kv(0);
  if (qt >= 1) {
    stage_kv(1);
    asm volatile("s_waitcnt vmcnt(4)" ::: "memory");
  } else {
    asm volatile("s_waitcnt vmcnt(0)" ::: "memory");
  }
  __builtin_amdgcn_s_barrier();
  asm volatile("" ::: "memory");

  bf16x8 aq[2];
  #pragma unroll
  for (int ks = 0; ks < 2; ++ks)
    aq[ks] = *(const bf16x8*)&Qs[(wave * 16 + l) * 64 + (((ks * 4 + quad) ^ (l & 7)) * 8)];

  f32x4 O[4];
  float mi_[4], li[4];
  #pragma unroll
  for (int f = 0; f < 4; ++f) O[f] = fzero;
  #pragma unroll
  for (int r = 0; r < 4; ++r) { mi_[r] = -1e30f; li[r] = 0.f; }

  for (int jt = 0; jt <= qt; ++jt) {
    const int s = jt % 3;
    if (jt > 0) {
      if (jt + 1 <= qt) { asm volatile("s_waitcnt vmcnt(4)" ::: "memory"); }
      else              { asm volatile("s_waitcnt vmcnt(0)" ::: "memory"); }
      __builtin_amdgcn_s_barrier();
      asm volatile("" ::: "memory");
    }
    if (jt + 2 <= qt) stage_kv((jt + 2) % 3);

    f32x4 S[4];
    #pragma unroll
    for (int f = 0; f < 4; ++f) S[f] = fzero;
    #pragma unroll
    for (int ks = 0; ks < 2; ++ks) {
      #pragma unroll
      for (int f = 0; f < 4; ++f) {
        bf16x8 bk = *(const bf16x8*)&Ks[s][(f * 16 + l) * 64 + (((ks * 4 + quad) ^ (l & 7)) * 8)];
        S[f] = __builtin_amdgcn_mfma_f32_16x16x32_bf16(aq[ks], bk, S[f], 0, 0, 0);
      }
    }
    const bool diag = (jt == qt);
    #pragma unroll
    for (int f = 0; f < 4; ++f)
      #pragma unroll
      for (int r = 0; r < 4; ++r) {
        float v = S[f][r] * 0.125f;
        if (diag && (f * 16 + l > wave * 16 + quad * 4 + r)) v = -1e30f;
        S[f][r] = v;
      }
    #pragma unroll
    for (int r = 0; r < 4; ++r) {
      float mx = fmaxf(fmaxf(S[0][r], S[1][r]), fmaxf(S[2][r], S[3][r]));
      #pragma unroll
      for (int o = 8; o; o >>= 1) mx = fmaxf(mx, __shfl_xor(mx, o));
      float mnew = fmaxf(mi_[r], mx);
      float alr = __expf(mi_[r] - mnew);
      float sum = 0.f;
      #pragma unroll
      for (int f = 0; f < 4; ++f) {
        float e = __expf(S[f][r] - mnew);
        S[f][r] = e;
        sum += e;
      }
      #pragma unroll
      for (int o = 8; o; o >>= 1) sum += __shfl_xor(sum, o);
      li[r] = li[r] * alr + sum;
      #pragma unroll
      for (int f = 0; f < 4; ++f) O[f][r] *= alr;
      mi_[r] = mnew;
    }
    #pragma unroll
    for (int f = 0; f < 4; ++f)
      #pragma unroll
      for (int r = 0; r < 4; ++r) {
        int i = quad * 4 + r;
        int j = f * 16 + l;
        int pch = (j >> 3) ^ (i & 7);
        Ps[wave * 1024 + i * 64 + pch * 8 + (j & 7)] = f2bf(S[f][r]);
      }
    #pragma unroll
    for (int ks = 0; ks < 2; ++ks) {
      bf16x8 ap = *(const bf16x8*)&Ps[wave * 1024 + l * 64 + (((ks * 4 + quad) ^ (l & 7)) * 8)];
      #pragma unroll
      for (int f = 0; f < 4; ++f) {
        bf16x8 bv = *(const bf16x8*)&Vs[s][(f * 16 + l) * 64 + (((ks * 4 + quad) ^ (l & 7)) * 8)];
        O[f] = __builtin_amdgcn_mfma_f32_16x16x32_bf16(ap, bv, O[f], 0, 0, 0);
      }
    }
  }
  float inv[4];
  #pragma unroll
  for (int r = 0; r < 4; ++r) inv[r] = __fdividef(1.f, li[r]);
  #pragma unroll
  for (int f = 0; f < 4; ++f)
    #pragma unroll
    for (int r = 0; r < 4; ++r) {
      int t = q0 + wave * 16 + quad * 4 + r;
      int dd = f * 16 + l;
      ob[((long)(b * 1024 + t) * 12 + hh) * 64 + dd] = f2bf(O[f][r] * inv[r]);  // (B,T,H,D)
    }
  #pragma unroll
  for (int r = 0; r < 4; ++r) {
    float rsum = 0.f;
    #pragma unroll
    for (int f = 0; f < 4; ++f) { float v = O[f][r] * inv[r]; rsum += v * v; }
    #pragma unroll
    for (int o = 8; o; o >>= 1) rsum += __shfl_xor(rsum, o);
    if (l == 0) {
      int t = q0 + wave * 16 + quad * 4 + r;
      atomicAdd(&orow2[b * 1024 + t], rsum);
    }
  }
}

// ---------------- host ------------------------------------------------------
extern "C" void kernel_launch(void* const* d_in, const int* in_sizes, int n_in,
                              void* d_out, int out_size, void* d_ws, size_t ws_size,
                              hipStream_t stream) {
  (void)in_sizes; (void)n_in; (void)out_size;
  char* w = (char*)d_ws;
  size_t off = 0;
  auto alloc = [&](size_t bytes) -> void* {
    void* p = w + off;
    off = (off + bytes + 255) & ~(size_t)255;
    return p;
  };
  float* rope            = (float*)alloc(65536 * 4);
  unsigned short* wtqkv  = (unsigned short*)alloc((size_t)2304 * 768 * 2);
  unsigned short* wtao   = (unsigned short*)alloc((size_t)768 * 768 * 2);
  unsigned short* wtfc   = (unsigned short*)alloc((size_t)3072 * 768 * 2);
  unsigned short* wtgate = (unsigned short*)alloc((size_t)3072 * 768 * 2);
  unsigned short* wtproj = (unsigned short*)alloc((size_t)768 * 3072 * 2);
  float* zeroed          = (float*)alloc(14080 * 4);   // wcol2(9984) + orow2(2048) + mrow2(2048)
  unsigned short* h1     = (unsigned short*)alloc((size_t)2048 * 768 * 2);
  float* hrow1           = (float*)alloc(2048 * 4);
  unsigned short* qbuf   = (unsigned short*)alloc((size_t)2048 * 768 * 2);
  unsigned short* kbuf   = (unsigned short*)alloc((size_t)2048 * 768 * 2);
  unsigned short* vbuf   = (unsigned short*)alloc((size_t)2048 * 768 * 2);
  unsigned short* obuf   = (unsigned short*)alloc((size_t)2048 * 768 * 2);
  float* xo              = (float*)alloc((size_t)2048 * 768 * 4);
  unsigned short* h2     = (unsigned short*)alloc((size_t)2048 * 768 * 2);
  float* hrow2           = (float*)alloc(2048 * 4);
  unsigned short* mlp    = (unsigned short*)alloc((size_t)2048 * 3072 * 2);
  unsigned short* slabs  = (unsigned short*)alloc((size_t)4 * 2048 * 768 * 2);  // bf16 split-K partials
  if (off > ws_size) return;

  float* wcol2  = zeroed;
  float* orow2  = zeroed + 9984;
  float* mrow2  = zeroed + 9984 + 2048;
  float* c_qkv  = wcol2 + 0;
  float* c_ao   = wcol2 + 2304;
  float* c_fc   = wcol2 + 3072;
  float* c_gate = wcol2 + 6144;
  float* c_proj = wcol2 + 9216;

  const float* xin = (const float*)d_in[0];

  hipMemsetAsync(zeroed, 0, 14080 * 4, stream);

  PrepArgs pa;
  pa.rope = rope;
  pa.W[0] = (const float*)d_in[3];  pa.Wt[0] = wtqkv;  pa.cn[0] = c_qkv;  pa.N[0] = 2304;
  pa.W[1] = (const float*)d_in[6];  pa.Wt[1] = wtao;   pa.cn[1] = c_ao;   pa.N[1] = 768;
  pa.W[2] = (const float*)d_in[10]; pa.Wt[2] = wtfc;   pa.cn[2] = c_fc;   pa.N[2] = 3072;
  pa.W[3] = (const float*)d_in[13]; pa.Wt[3] = wtgate; pa.cn[3] = c_gate; pa.N[3] = 3072;
  pa.W[4] = (const float*)d_in[16]; pa.Wt[4] = wtproj; pa.cn[4] = c_proj; pa.N[4] = 768;
  // 64x64 tiles: qkv 36x12=432, ao 12x12=144, fc 48x12=576, gate 576, proj 12x48=576
  pa.off[0] = 0; pa.off[1] = 432; pa.off[2] = 576; pa.off[3] = 1152;
  pa.off[4] = 1728; pa.off[5] = 2304;
  pa.x = xin; pa.g1s = (const float*)d_in[2]; pa.h1 = h1; pa.hrow1 = hrow1;
  k_prep<<<4608, 256, 0, stream>>>(pa);

  GemmArgs gq = {};
  gq.A = h1; gq.Bt = wtqkv; gq.arow2 = hrow1; gq.wcol2 = c_qkv;
  gq.bias = (const float*)d_in[4]; gq.alpha = (const float*)d_in[5];
  gq.N = 2304; gq.ks = 768;
  gq.rope = rope; gq.qo = qbuf; gq.ko = kbuf; gq.vo = vbuf;
  k_gemm64<M_QKV, 32, 36><<<1152, 256, 0, stream>>>(gq);

  k_attn<<<384, 256, 0, stream>>>(qbuf, kbuf, vbuf, obuf, orow2);

  GemmArgs ga = {};
  ga.A = obuf; ga.Bt = wtao; ga.arow2 = orow2; ga.wcol2 = c_ao;
  ga.bias = (const float*)d_in[7]; ga.alpha = (const float*)d_in[8];
  ga.N = 768; ga.ks = 768;
  ga.xf = xin; ga.xo = xo;
  k_gemm64<M_AO, 32, 12><<<384, 256, 0, stream>>>(ga);

  k_ln<<<2048, 256, 0, stream>>>(xo, (const float*)d_in[9], h2, hrow2);

  MlpArgs gm = {};
  gm.A = h2; gm.Bf = wtfc; gm.Bg = wtgate; gm.arow2 = hrow2;
  gm.w2f = c_fc; gm.w2g = c_gate;
  gm.bf = (const float*)d_in[11]; gm.bg = (const float*)d_in[14];
  gm.af_ = (const float*)d_in[12]; gm.ag_ = (const float*)d_in[15];
  gm.mlp = mlp; gm.mrow2 = mrow2;
  k_mlp<<<768, 256, 0, stream>>>(gm);

  GemmArgs gp = {};
  gp.A = mlp; gp.Bt = wtproj;
  gp.N = 768; gp.ks = 3072;
  gp.partb = slabs;
  k_gemm<M_PART, 24, 32, 6, 4><<<768, 256, 0, stream>>>(gp);

  EpiArgs ge = {};
  ge.slab = slabs; ge.arow2 = mrow2; ge.wcol2 = c_proj;
  ge.bias = (const float*)d_in[17]; ge.alpha = (const float*)d_in[18];
  ge.xo = xo; ge.outf = (float*)d_out;
  k_proj_epi<<<1536, 256, 0, stream>>>(ge);
}